// Round 4
// baseline (303.906 us; speedup 1.0000x reference)
//
#include <hip/hip_runtime.h>
#include <hip/hip_bf16.h>
#include <math.h>

#define Bb 2
#define Tt 2048
#define Cc 1024
#define Hh 16
#define HDd 64

typedef __attribute__((ext_vector_type(8))) short short8;
typedef __attribute__((ext_vector_type(4))) short short4v;
typedef __attribute__((ext_vector_type(4))) float f32x4;

#if defined(__has_builtin)
#if __has_builtin(__builtin_amdgcn_global_load_lds)
#define USE_GLL 1
#endif
#endif
#define AS_GLOBAL __attribute__((address_space(1)))
#define AS_LDS    __attribute__((address_space(3)))

__device__ __forceinline__ float bf2f(unsigned short u){
  union { unsigned int i; float f; } v; v.i = ((unsigned int)u)<<16; return v.f;
}
__device__ __forceinline__ unsigned short f2bf(float f){
  union { float f; unsigned int i; } v; v.f = f;
  unsigned int x = v.i;
  return (unsigned short)((x + 0x7fffu + ((x>>16)&1u)) >> 16);
}
// hardware packed f32->bf16 (RNE), 2 values -> 1 u32
__device__ __forceinline__ unsigned int cvtpk_bf16(float lo, float hi){
  unsigned int r;
  asm("v_cvt_pk_bf16_f32 %0, %1, %2" : "=v"(r) : "v"(lo), "v"(hi));
  return r;
}
// 16x16x16 bf16 MFMA (2-VGPR operands)
__device__ __forceinline__ f32x4 mfma16(short4v a, short4v b, f32x4 c){
#if defined(__has_builtin)
#if __has_builtin(__builtin_amdgcn_mfma_f32_16x16x16_bf16)
  return __builtin_amdgcn_mfma_f32_16x16x16_bf16(a, b, c, 0, 0, 0);
#elif __has_builtin(__builtin_amdgcn_mfma_f32_16x16x16bf16_1k)
  return __builtin_amdgcn_mfma_f32_16x16x16bf16_1k(a, b, c, 0, 0, 0);
#else
  asm("v_mfma_f32_16x16x16_bf16 %0, %1, %2, %3" : "=v"(c) : "v"(a), "v"(b), "0"(c));
  return c;
#endif
#else
  asm("v_mfma_f32_16x16x16_bf16 %0, %1, %2, %3" : "=v"(c) : "v"(a), "v"(b), "0"(c));
  return c;
#endif
}

// ---------------- fp32 -> bf16 convert (vector) ----------------
__global__ __launch_bounds__(256) void k_f2b(const float* __restrict__ in,
                                             unsigned short* __restrict__ out, int n){
  int i = (blockIdx.x*256 + threadIdx.x)*4;
  if (i >= n) return;
  float4 v = *(const float4*)(in + i);
  unsigned long long p = (unsigned long long)f2bf(v.x)
                       | ((unsigned long long)f2bf(v.y)<<16)
                       | ((unsigned long long)f2bf(v.z)<<32)
                       | ((unsigned long long)f2bf(v.w)<<48);
  *(unsigned long long*)(out + i) = p;
}

// ---------------- transpose + convert: W[K][N] f32 -> Wt[N][K] bf16 ----------------
__global__ __launch_bounds__(256) void k_transpose_f2b(const float* __restrict__ in,
                                                       unsigned short* __restrict__ out,
                                                       int K, int N){
  __shared__ float tile[32][33];
  int kb = blockIdx.y*32, nb = blockIdx.x*32;
  int tx = threadIdx.x, ty = threadIdx.y; // (32, 8)
  #pragma unroll
  for (int i=0;i<4;i++)
    tile[ty+i*8][tx] = in[(size_t)(kb+ty+i*8)*N + nb + tx];
  __syncthreads();
  #pragma unroll
  for (int i=0;i<4;i++)
    out[(size_t)(nb+ty+i*8)*K + kb + tx] = f2bf(tile[tx][ty+i*8]);
}

// ---------------- scan: global token counts -> per-batch cumulative rotations ----------------
__global__ __launch_bounds__(1024) void k_scan(const int* __restrict__ tok,
                                               float* __restrict__ rot){
  __shared__ int cnt[2048];
  __shared__ float vals[2048];
  __shared__ float psum[1024];
  int b = blockIdx.x;
  int tid = threadIdx.x;
  cnt[tid] = 0; cnt[tid+1024] = 0;
  __syncthreads();
  // reference's fancy-indexing scatters ALL batches' tokens into every batch's counts
  for (int i = tid; i < Bb*Tt; i += 1024) atomicAdd(&cnt[tok[i]], 1);
  __syncthreads();
  for (int i = tid; i < Tt; i += 1024){
    int idx = tok[b*Tt + i];
    vals[i] = 1.0f / ((float)cnt[idx] + 1e-10f);
  }
  __syncthreads();
  float s0 = vals[2*tid], s1 = vals[2*tid+1];
  psum[tid] = s0 + s1;
  __syncthreads();
  for (int off=1; off<1024; off<<=1){
    float add = (tid>=off) ? psum[tid-off] : 0.0f;
    __syncthreads();
    psum[tid] += add;
    __syncthreads();
  }
  float base = (tid>0) ? psum[tid-1] : 0.0f;
  rot[b*Tt + 2*tid]   = base + s0;
  rot[b*Tt + 2*tid+1] = base + s0 + s1;
}

// ---------------- cos/sin tables from rotations ----------------
__global__ __launch_bounds__(256) void k_tables(const float* __restrict__ rot,
                                                float* __restrict__ cos_t,
                                                float* __restrict__ sin_t){
  int i = blockIdx.x*256 + threadIdx.x;   // over Bb*Tt*32
  int j = i & 31;
  int bt = i >> 5;
  float invf = exp2f(-(float)j * 0.4152410118609203f);  // 10000^(-j/32)
  float ang = rot[bt] * invf;
  cos_t[i] = cosf(ang);
  sin_t[i] = sinf(ang);
}

// ---------------- 128x128-tile bf16 MFMA GEMM: C = A[M][K] @ Bt[N][K]^T + bias ----------------
template<int OUTF32>
__global__ __launch_bounds__(256) void k_gemm128(const unsigned short* __restrict__ A,
                                                 const unsigned short* __restrict__ Bt,
                                                 const float* __restrict__ bias,
                                                 void* __restrict__ Cout,
                                                 int M, int N, int K){
  __shared__ unsigned short As[128][32];
  __shared__ unsigned short Bs[128][32];
  int mb = blockIdx.y*128, nb = blockIdx.x*128;
  int tid = threadIdx.x;
  int wave = tid>>6, lane = tid&63;
  int wr = wave>>1, wc = wave&1;
  int lrow = lane&15, lhi = lane>>4;
  f32x4 acc[4][4] = {};
  int r0 = tid>>2;          // 0..63 (rows r0 and r0+64)
  int c0 = (tid&3)*8;       // 16B column group
  const unsigned short* Arow0 = A  + (size_t)(mb + r0)*K      + c0;
  const unsigned short* Arow1 = A  + (size_t)(mb + r0 + 64)*K + c0;
  const unsigned short* Brow0 = Bt + (size_t)(nb + r0)*K      + c0;
  const unsigned short* Brow1 = Bt + (size_t)(nb + r0 + 64)*K + c0;
#ifdef USE_GLL
  for (int kb=0; kb<K; kb+=32){
    __builtin_amdgcn_global_load_lds((const AS_GLOBAL void*)(Arow0 + kb),
                                     (AS_LDS void*)&As[r0][c0],    16, 0, 0);
    __builtin_amdgcn_global_load_lds((const AS_GLOBAL void*)(Arow1 + kb),
                                     (AS_LDS void*)&As[r0+64][c0], 16, 0, 0);
    __builtin_amdgcn_global_load_lds((const AS_GLOBAL void*)(Brow0 + kb),
                                     (AS_LDS void*)&Bs[r0][c0],    16, 0, 0);
    __builtin_amdgcn_global_load_lds((const AS_GLOBAL void*)(Brow1 + kb),
                                     (AS_LDS void*)&Bs[r0+64][c0], 16, 0, 0);
    __syncthreads();
    short8 af[4], bf[4];
    #pragma unroll
    for (int m=0;m<4;m++) af[m] = *(const short8*)&As[64*wr + 16*m + lrow][8*lhi];
    #pragma unroll
    for (int n=0;n<4;n++) bf[n] = *(const short8*)&Bs[64*wc + 16*n + lrow][8*lhi];
    #pragma unroll
    for (int m=0;m<4;m++)
      #pragma unroll
      for (int n=0;n<4;n++)
        acc[m][n] = __builtin_amdgcn_mfma_f32_16x16x32_bf16(af[m], bf[n], acc[m][n], 0,0,0);
    __syncthreads();
  }
#else
  for (int kb=0; kb<K; kb+=32){
    int4 a0 = *(const int4*)(Arow0 + kb);
    int4 a1 = *(const int4*)(Arow1 + kb);
    int4 b0 = *(const int4*)(Brow0 + kb);
    int4 b1 = *(const int4*)(Brow1 + kb);
    __syncthreads();
    *(int4*)&As[r0][c0]    = a0;
    *(int4*)&As[r0+64][c0] = a1;
    *(int4*)&Bs[r0][c0]    = b0;
    *(int4*)&Bs[r0+64][c0] = b1;
    __syncthreads();
    short8 af[4], bf[4];
    #pragma unroll
    for (int m=0;m<4;m++) af[m] = *(const short8*)&As[64*wr + 16*m + lrow][8*lhi];
    #pragma unroll
    for (int n=0;n<4;n++) bf[n] = *(const short8*)&Bs[64*wc + 16*n + lrow][8*lhi];
    #pragma unroll
    for (int m=0;m<4;m++)
      #pragma unroll
      for (int n=0;n<4;n++)
        acc[m][n] = __builtin_amdgcn_mfma_f32_16x16x32_bf16(af[m], bf[n], acc[m][n], 0,0,0);
  }
#endif
  #pragma unroll
  for (int m=0;m<4;m++)
    #pragma unroll
    for (int n=0;n<4;n++)
      #pragma unroll
      for (int q=0;q<4;q++){
        int row = mb + 64*wr + 16*m + 4*lhi + q;
        int col = nb + 64*wc + 16*n + lrow;
        float v = acc[m][n][q] + bias[col];
        if (OUTF32) ((float*)Cout)[(size_t)row*N + col] = v;
        else ((unsigned short*)Cout)[(size_t)row*N + col] = f2bf(v);
      }
}

// ---------------- post-QKV: rope, overwrites, v-scale; write Q,K,[VT transposed] ----------------
__global__ __launch_bounds__(256) void k_post(const unsigned short* __restrict__ qkv,
                                              const float* __restrict__ cos_t,
                                              const float* __restrict__ sin_t,
                                              const float* __restrict__ cum,
                                              unsigned short* __restrict__ Q,
                                              unsigned short* __restrict__ K,
                                              unsigned short* __restrict__ VT){
  __shared__ unsigned short vt[64][66];
  int b = blockIdx.z, h = blockIdx.y, tb = blockIdx.x*64;
  int d0 = threadIdx.x & 31, tsub = threadIdx.x >> 5; // 32 x 8
  const float scale = 0.125f;
  #pragma unroll
  for (int i=0;i<8;i++){
    int t = tb + tsub + i*8;
    size_t rowoff = ((size_t)b*Tt + t)*3*Cc + (size_t)h*HDd;
    float c = cos_t[((size_t)b*Tt + t)*32 + d0];
    float s = sin_t[((size_t)b*Tt + t)*32 + d0];
    float q0 = bf2f(qkv[rowoff + d0]);
    float q1 = bf2f(qkv[rowoff + d0 + 32]);
    float k0 = bf2f(qkv[rowoff + Cc + d0]);
    float k1 = bf2f(qkv[rowoff + Cc + d0 + 32]);
    float v0 = bf2f(qkv[rowoff + 2*Cc + d0]);
    float v1 = bf2f(qkv[rowoff + 2*Cc + d0 + 32]);
    float qa = q0*c - q1*s, qb = q1*c + q0*s;
    float ka = k0*c - k1*s, kb = k1*c + k0*s;
    float cs = cum[b*Tt + t];
    if (d0 == 31){ qb = 1.0f; kb = cs; }   // last dim (d=63) overwrites, post-rope
    qa *= scale; qb *= scale;              // fold softmax scale into Q
    float ev = expf(cs);
    v0 *= ev; v1 *= ev;
    size_t qrow = (((size_t)b*Hh + h)*Tt + t)*HDd;
    Q[qrow + d0]      = f2bf(qa);
    Q[qrow + d0 + 32] = f2bf(qb);
    K[qrow + d0]      = f2bf(ka);
    K[qrow + d0 + 32] = f2bf(kb);
    vt[tsub + i*8][d0]      = f2bf(v0);
    vt[tsub + i*8][d0 + 32] = f2bf(v1);
  }
  __syncthreads();
  #pragma unroll
  for (int i=0;i<16;i++){
    int d  = (threadIdx.x >> 6) + i*4;
    int ttl = threadIdx.x & 63;
    VT[(((size_t)b*Hh + h)*HDd + d)*Tt + tb + ttl] = vt[ttl][d];
  }
}

// ---------------- flash attention v4: swapped QK^T, fully in-register P ----------------
// mfma(Kfrag, Qfrag) -> lane holds S[k=4*(lane>>4)+r][q=lane&15]; that is exactly
// the A-operand layout of 16x16x16 MFMA for P@V, so P never leaves the lane:
// exp -> cvt_pk_bf16 (2 instrs / 16-k block) -> PV. No LDS, no P roundtrip.
// Fixed m=0 softmax (scores bounded), l = per-lane f32 partial, reduced at end.
// Balanced mirrored strips (low 64s.. / high 1984-64s..) as before.
__global__ __launch_bounds__(256) void k_attn4(const unsigned short* __restrict__ Q,
                                               const unsigned short* __restrict__ K,
                                               const unsigned short* __restrict__ VT,
                                               unsigned short* __restrict__ Y){
  int bh = blockIdx.y; int b = bh >> 4, h = bh & 15;
  int wave = threadIdx.x>>6, lane = threadIdx.x&63;
  int lrow = lane&15, lhi = lane>>4;
  const unsigned short* Qh = Q + (((size_t)b*Hh + h)*Tt)*HDd;
  const unsigned short* Kh = K + (((size_t)b*Hh + h)*Tt)*HDd;
  const unsigned short* Vh = VT + (((size_t)b*Hh + h)*HDd)*Tt;
  int s_ = blockIdx.x;                     // 0..15
  int qL0 = 64*s_ + 16*wave;               // low strip rows
  int qH0 = 1984 - 64*s_ + 16*wave;        // mirrored high strip rows
  short8 qfL[2], qfH[2];
  qfL[0] = *(const short8*)&Qh[(size_t)(qL0+lrow)*HDd + 8*lhi];
  qfL[1] = *(const short8*)&Qh[(size_t)(qL0+lrow)*HDd + 32 + 8*lhi];
  qfH[0] = *(const short8*)&Qh[(size_t)(qH0+lrow)*HDd + 8*lhi];
  qfH[1] = *(const short8*)&Qh[(size_t)(qH0+lrow)*HDd + 32 + 8*lhi];
  f32x4 oL[4] = {}, oH[4] = {};            // [d-tile j'], rows q=4*lhi+r
  float lsL = 0.0f, lsH = 0.0f;            // per-lane l partial for q=lrow
  int rowL = qL0 + lrow, rowH = qH0 + lrow;  // this lane's q-row (for masking)
  int ntL = qL0/64 + 1;
  int ntH = qH0/64 + 1;

  for (int kt=0; kt<ntH; kt++){
    int k0 = kt*64;
    bool doL = (kt < ntL);
    f32x4 sL[4] = {}, sH[4] = {};
    // QK^T swapped: A=K rows (k), B=Q rows (q). D: lane = S[k=16j+4*lhi+r][q=lrow]
    #pragma unroll
    for (int j=0;j<4;j++){
      #pragma unroll
      for (int ks=0;ks<2;ks++){
        short8 kf = *(const short8*)&Kh[(size_t)(k0 + 16*j + lrow)*HDd + 32*ks + 8*lhi];
        sH[j] = __builtin_amdgcn_mfma_f32_16x16x32_bf16(kf, qfH[ks], sH[j], 0,0,0);
        if (doL) sL[j] = __builtin_amdgcn_mfma_f32_16x16x32_bf16(kf, qfL[ks], sL[j], 0,0,0);
      }
    }
    // exp + pack to bf16 A-fragments (in-lane), accumulate l
    short4v paH[4], paL[4];
    {
      bool diagH = (k0 + 63 >= qH0);
      #pragma unroll
      for (int j=0;j<4;j++){
        int kbase = k0 + 16*j + 4*lhi;
        float p0 = __expf(sH[j][0]);
        float p1 = __expf(sH[j][1]);
        float p2 = __expf(sH[j][2]);
        float p3 = __expf(sH[j][3]);
        if (diagH){
          if (kbase + 0 > rowH) p0 = 0.0f;
          if (kbase + 1 > rowH) p1 = 0.0f;
          if (kbase + 2 > rowH) p2 = 0.0f;
          if (kbase + 3 > rowH) p3 = 0.0f;
        }
        lsH += (p0 + p1) + (p2 + p3);
        union { unsigned int u[2]; short4v v; } pk;
        pk.u[0] = cvtpk_bf16(p0, p1);
        pk.u[1] = cvtpk_bf16(p2, p3);
        paH[j] = pk.v;
      }
    }
    if (doL){
      bool diagL = (k0 + 63 >= qL0);
      #pragma unroll
      for (int j=0;j<4;j++){
        int kbase = k0 + 16*j + 4*lhi;
        float p0 = __expf(sL[j][0]);
        float p1 = __expf(sL[j][1]);
        float p2 = __expf(sL[j][2]);
        float p3 = __expf(sL[j][3]);
        if (diagL){
          if (kbase + 0 > rowL) p0 = 0.0f;
          if (kbase + 1 > rowL) p1 = 0.0f;
          if (kbase + 2 > rowL) p2 = 0.0f;
          if (kbase + 3 > rowL) p3 = 0.0f;
        }
        lsL += (p0 + p1) + (p2 + p3);
        union { unsigned int u[2]; short4v v; } pk;
        pk.u[0] = cvtpk_bf16(p0, p1);
        pk.u[1] = cvtpk_bf16(p2, p3);
        paL[j] = pk.v;
      }
    }
    // PV: O[q][d] += P[q][k] V[k][d]; B-frag = VT rows (d) over k, shared by strips
    #pragma unroll
    for (int jp=0;jp<4;jp++){
      #pragma unroll
      for (int j=0;j<4;j++){
        short4v vf = *(const short4v*)&Vh[(size_t)(16*jp + lrow)*Tt + k0 + 16*j + 4*lhi];
        oH[jp] = mfma16(paH[j], vf, oH[jp]);
        if (doL) oL[jp] = mfma16(paL[j], vf, oL[jp]);
      }
    }
  }
  // reduce l over the 4 lane-replicas (lanes 16 apart hold same q)
  lsL += __shfl_xor(lsL, 16); lsL += __shfl_xor(lsL, 32);
  lsH += __shfl_xor(lsH, 16); lsH += __shfl_xor(lsH, 32);
  float invLl = 1.0f / lsL, invHl = 1.0f / lsH;
  // output rows are q=4*lhi+r; fetch matching 1/l via lane shuffle
  float invLr[4], invHr[4];
  #pragma unroll
  for (int r=0;r<4;r++){
    invLr[r] = __shfl(invLl, 4*lhi + r);
    invHr[r] = __shfl(invHl, 4*lhi + r);
  }
  #pragma unroll
  for (int jp=0;jp<4;jp++)
    #pragma unroll
    for (int r=0;r<4;r++){
      int rqL = qL0 + 4*lhi + r;
      int rqH = qH0 + 4*lhi + r;
      int col = h*HDd + 16*jp + lrow;
      Y[((size_t)b*Tt + rqL)*Cc + col] = f2bf(oL[jp][r] * invLr[r]);
      Y[((size_t)b*Tt + rqH)*Cc + col] = f2bf(oH[jp][r] * invHr[r]);
    }
}

extern "C" void kernel_launch(void* const* d_in, const int* in_sizes, int n_in,
                              void* d_out, int out_size, void* d_ws, size_t ws_size,
                              hipStream_t stream){
  const float* x     = (const float*)d_in[0];
  const float* cum   = (const float*)d_in[1];
  const int*   tok   = (const int*)d_in[3];
  const float* Wqkv  = (const float*)d_in[4];
  const float* bqkv  = (const float*)d_in[5];
  const float* Wproj = (const float*)d_in[6];
  const float* bproj = (const float*)d_in[7];

  char* ws = (char*)d_ws;
  size_t off = 0;
  auto alloc = [&](size_t bytes)->void*{
    void* p = ws + off; off += (bytes + 255) & ~(size_t)255; return p;
  };
  unsigned short* wqkvT = (unsigned short*)alloc((size_t)3072*1024*2);
  unsigned short* wprojT= (unsigned short*)alloc((size_t)1024*1024*2);
  unsigned short* xb    = (unsigned short*)alloc((size_t)4096*1024*2); // reused as Y
  unsigned short* qkv   = (unsigned short*)alloc((size_t)4096*3072*2);
  unsigned short* Qb    = (unsigned short*)alloc((size_t)Bb*Hh*Tt*HDd*2);
  unsigned short* Kb    = (unsigned short*)alloc((size_t)Bb*Hh*Tt*HDd*2);
  unsigned short* VTb   = (unsigned short*)alloc((size_t)Bb*Hh*Tt*HDd*2);
  float* rot            = (float*)alloc((size_t)Bb*Tt*4);
  float* cos_t          = (float*)alloc((size_t)Bb*Tt*32*4);
  float* sin_t          = (float*)alloc((size_t)Bb*Tt*32*4);
  unsigned short* Y     = xb; // alias: xb dead after QKV GEMM

  k_f2b<<<dim3((4096*1024/4 + 255)/256), dim3(256), 0, stream>>>(x, xb, 4096*1024);
  k_transpose_f2b<<<dim3(3072/32, 1024/32), dim3(32,8), 0, stream>>>(Wqkv, wqkvT, 1024, 3072);
  k_transpose_f2b<<<dim3(1024/32, 1024/32), dim3(32,8), 0, stream>>>(Wproj, wprojT, 1024, 1024);
  k_scan<<<dim3(Bb), dim3(1024), 0, stream>>>(tok, rot);
  k_tables<<<dim3(Bb*Tt*32/256), dim3(256), 0, stream>>>(rot, cos_t, sin_t);
  k_gemm128<0><<<dim3(3072/128, 4096/128), dim3(256), 0, stream>>>(xb, wqkvT, bqkv, qkv, 4096, 3072, 1024);
  k_post<<<dim3(Tt/64, Hh, Bb), dim3(256), 0, stream>>>(qkv, cos_t, sin_t, cum, Qb, Kb, VTb);
  k_attn4<<<dim3(16, Bb*Hh), dim3(256), 0, stream>>>(Qb, Kb, VTb, Y);
  k_gemm128<1><<<dim3(1024/128, 4096/128), dim3(256), 0, stream>>>(Y, wprojT, bproj, (float*)d_out, 4096, 1024, 1024);
}

// Round 5
// 267.585 us; speedup vs baseline: 1.1357x; 1.1357x over previous
//
#include <hip/hip_runtime.h>
#include <hip/hip_bf16.h>
#include <math.h>

#define Bb 2
#define Tt 2048
#define Cc 1024
#define Hh 16
#define HDd 64

typedef __attribute__((ext_vector_type(8))) short short8;
typedef __attribute__((ext_vector_type(4))) short short4v;
typedef __attribute__((ext_vector_type(4))) float f32x4;

#if defined(__has_builtin)
#if __has_builtin(__builtin_amdgcn_global_load_lds)
#define USE_GLL 1
#endif
#endif
#define AS_GLOBAL __attribute__((address_space(1)))
#define AS_LDS    __attribute__((address_space(3)))

__device__ __forceinline__ float bf2f(unsigned short u){
  union { unsigned int i; float f; } v; v.i = ((unsigned int)u)<<16; return v.f;
}
__device__ __forceinline__ unsigned short f2bf(float f){
  union { float f; unsigned int i; } v; v.f = f;
  unsigned int x = v.i;
  return (unsigned short)((x + 0x7fffu + ((x>>16)&1u)) >> 16);
}
// hardware packed f32->bf16 (RNE), 2 values -> 1 u32
__device__ __forceinline__ unsigned int cvtpk_bf16(float lo, float hi){
  unsigned int r;
  asm("v_cvt_pk_bf16_f32 %0, %1, %2" : "=v"(r) : "v"(lo), "v"(hi));
  return r;
}
// 16x16x16 bf16 MFMA (2-VGPR operands)
__device__ __forceinline__ f32x4 mfma16(short4v a, short4v b, f32x4 c){
#if defined(__has_builtin)
#if __has_builtin(__builtin_amdgcn_mfma_f32_16x16x16_bf16)
  return __builtin_amdgcn_mfma_f32_16x16x16_bf16(a, b, c, 0, 0, 0);
#elif __has_builtin(__builtin_amdgcn_mfma_f32_16x16x16bf16_1k)
  return __builtin_amdgcn_mfma_f32_16x16x16bf16_1k(a, b, c, 0, 0, 0);
#else
  asm("v_mfma_f32_16x16x16_bf16 %0, %1, %2, %3" : "=v"(c) : "v"(a), "v"(b), "0"(c));
  return c;
#endif
#else
  asm("v_mfma_f32_16x16x16_bf16 %0, %1, %2, %3" : "=v"(c) : "v"(a), "v"(b), "0"(c));
  return c;
#endif
}

// ---------------- fp32 -> bf16 convert (vector) ----------------
__global__ __launch_bounds__(256) void k_f2b(const float* __restrict__ in,
                                             unsigned short* __restrict__ out, int n){
  int i = (blockIdx.x*256 + threadIdx.x)*4;
  if (i >= n) return;
  float4 v = *(const float4*)(in + i);
  unsigned long long p = (unsigned long long)f2bf(v.x)
                       | ((unsigned long long)f2bf(v.y)<<16)
                       | ((unsigned long long)f2bf(v.z)<<32)
                       | ((unsigned long long)f2bf(v.w)<<48);
  *(unsigned long long*)(out + i) = p;
}

// ---------------- transpose + convert: W[K][N] f32 -> Wt[N][K] bf16 ----------------
__global__ __launch_bounds__(256) void k_transpose_f2b(const float* __restrict__ in,
                                                       unsigned short* __restrict__ out,
                                                       int K, int N){
  __shared__ float tile[32][33];
  int kb = blockIdx.y*32, nb = blockIdx.x*32;
  int tx = threadIdx.x, ty = threadIdx.y; // (32, 8)
  #pragma unroll
  for (int i=0;i<4;i++)
    tile[ty+i*8][tx] = in[(size_t)(kb+ty+i*8)*N + nb + tx];
  __syncthreads();
  #pragma unroll
  for (int i=0;i<4;i++)
    out[(size_t)(nb+ty+i*8)*K + kb + tx] = f2bf(tile[tx][ty+i*8]);
}

// ---------------- scan: global token counts -> per-batch cumulative rotations ----------------
__global__ __launch_bounds__(1024) void k_scan(const int* __restrict__ tok,
                                               float* __restrict__ rot){
  __shared__ int cnt[2048];
  __shared__ float vals[2048];
  __shared__ float psum[1024];
  int b = blockIdx.x;
  int tid = threadIdx.x;
  cnt[tid] = 0; cnt[tid+1024] = 0;
  __syncthreads();
  // reference's fancy-indexing scatters ALL batches' tokens into every batch's counts
  for (int i = tid; i < Bb*Tt; i += 1024) atomicAdd(&cnt[tok[i]], 1);
  __syncthreads();
  for (int i = tid; i < Tt; i += 1024){
    int idx = tok[b*Tt + i];
    vals[i] = 1.0f / ((float)cnt[idx] + 1e-10f);
  }
  __syncthreads();
  float s0 = vals[2*tid], s1 = vals[2*tid+1];
  psum[tid] = s0 + s1;
  __syncthreads();
  for (int off=1; off<1024; off<<=1){
    float add = (tid>=off) ? psum[tid-off] : 0.0f;
    __syncthreads();
    psum[tid] += add;
    __syncthreads();
  }
  float base = (tid>0) ? psum[tid-1] : 0.0f;
  rot[b*Tt + 2*tid]   = base + s0;
  rot[b*Tt + 2*tid+1] = base + s0 + s1;
}

// ---------------- cos/sin tables from rotations ----------------
__global__ __launch_bounds__(256) void k_tables(const float* __restrict__ rot,
                                                float* __restrict__ cos_t,
                                                float* __restrict__ sin_t){
  int i = blockIdx.x*256 + threadIdx.x;   // over Bb*Tt*32
  int j = i & 31;
  int bt = i >> 5;
  float invf = exp2f(-(float)j * 0.4152410118609203f);  // 10000^(-j/32)
  float ang = rot[bt] * invf;
  cos_t[i] = cosf(ang);
  sin_t[i] = sinf(ang);
}

// ---------------- 128x128-tile bf16 MFMA GEMM: C = A[M][K] @ Bt[N][K]^T + bias ----------------
template<int OUTF32>
__global__ __launch_bounds__(256) void k_gemm128(const unsigned short* __restrict__ A,
                                                 const unsigned short* __restrict__ Bt,
                                                 const float* __restrict__ bias,
                                                 void* __restrict__ Cout,
                                                 int M, int N, int K){
  __shared__ unsigned short As[128][32];
  __shared__ unsigned short Bs[128][32];
  int mb = blockIdx.y*128, nb = blockIdx.x*128;
  int tid = threadIdx.x;
  int wave = tid>>6, lane = tid&63;
  int wr = wave>>1, wc = wave&1;
  int lrow = lane&15, lhi = lane>>4;
  f32x4 acc[4][4] = {};
  int r0 = tid>>2;          // 0..63 (rows r0 and r0+64)
  int c0 = (tid&3)*8;       // 16B column group
  const unsigned short* Arow0 = A  + (size_t)(mb + r0)*K      + c0;
  const unsigned short* Arow1 = A  + (size_t)(mb + r0 + 64)*K + c0;
  const unsigned short* Brow0 = Bt + (size_t)(nb + r0)*K      + c0;
  const unsigned short* Brow1 = Bt + (size_t)(nb + r0 + 64)*K + c0;
#ifdef USE_GLL
  for (int kb=0; kb<K; kb+=32){
    __builtin_amdgcn_global_load_lds((const AS_GLOBAL void*)(Arow0 + kb),
                                     (AS_LDS void*)&As[r0][c0],    16, 0, 0);
    __builtin_amdgcn_global_load_lds((const AS_GLOBAL void*)(Arow1 + kb),
                                     (AS_LDS void*)&As[r0+64][c0], 16, 0, 0);
    __builtin_amdgcn_global_load_lds((const AS_GLOBAL void*)(Brow0 + kb),
                                     (AS_LDS void*)&Bs[r0][c0],    16, 0, 0);
    __builtin_amdgcn_global_load_lds((const AS_GLOBAL void*)(Brow1 + kb),
                                     (AS_LDS void*)&Bs[r0+64][c0], 16, 0, 0);
    __syncthreads();
    short8 af[4], bf[4];
    #pragma unroll
    for (int m=0;m<4;m++) af[m] = *(const short8*)&As[64*wr + 16*m + lrow][8*lhi];
    #pragma unroll
    for (int n=0;n<4;n++) bf[n] = *(const short8*)&Bs[64*wc + 16*n + lrow][8*lhi];
    #pragma unroll
    for (int m=0;m<4;m++)
      #pragma unroll
      for (int n=0;n<4;n++)
        acc[m][n] = __builtin_amdgcn_mfma_f32_16x16x32_bf16(af[m], bf[n], acc[m][n], 0,0,0);
    __syncthreads();
  }
#else
  for (int kb=0; kb<K; kb+=32){
    int4 a0 = *(const int4*)(Arow0 + kb);
    int4 a1 = *(const int4*)(Arow1 + kb);
    int4 b0 = *(const int4*)(Brow0 + kb);
    int4 b1 = *(const int4*)(Brow1 + kb);
    __syncthreads();
    *(int4*)&As[r0][c0]    = a0;
    *(int4*)&As[r0+64][c0] = a1;
    *(int4*)&Bs[r0][c0]    = b0;
    *(int4*)&Bs[r0+64][c0] = b1;
    __syncthreads();
    short8 af[4], bf[4];
    #pragma unroll
    for (int m=0;m<4;m++) af[m] = *(const short8*)&As[64*wr + 16*m + lrow][8*lhi];
    #pragma unroll
    for (int n=0;n<4;n++) bf[n] = *(const short8*)&Bs[64*wc + 16*n + lrow][8*lhi];
    #pragma unroll
    for (int m=0;m<4;m++)
      #pragma unroll
      for (int n=0;n<4;n++)
        acc[m][n] = __builtin_amdgcn_mfma_f32_16x16x32_bf16(af[m], bf[n], acc[m][n], 0,0,0);
  }
#endif
  #pragma unroll
  for (int m=0;m<4;m++)
    #pragma unroll
    for (int n=0;n<4;n++)
      #pragma unroll
      for (int q=0;q<4;q++){
        int row = mb + 64*wr + 16*m + 4*lhi + q;
        int col = nb + 64*wc + 16*n + lrow;
        float v = acc[m][n][q] + bias[col];
        if (OUTF32) ((float*)Cout)[(size_t)row*N + col] = v;
        else ((unsigned short*)Cout)[(size_t)row*N + col] = f2bf(v);
      }
}

// ---------------- post-QKV: rope, overwrites, v-scale; write Q,K,[VT transposed] ----------------
__global__ __launch_bounds__(256) void k_post(const unsigned short* __restrict__ qkv,
                                              const float* __restrict__ cos_t,
                                              const float* __restrict__ sin_t,
                                              const float* __restrict__ cum,
                                              unsigned short* __restrict__ Q,
                                              unsigned short* __restrict__ K,
                                              unsigned short* __restrict__ VT){
  __shared__ unsigned short vt[64][66];
  int b = blockIdx.z, h = blockIdx.y, tb = blockIdx.x*64;
  int d0 = threadIdx.x & 31, tsub = threadIdx.x >> 5; // 32 x 8
  const float scale = 0.125f;
  #pragma unroll
  for (int i=0;i<8;i++){
    int t = tb + tsub + i*8;
    size_t rowoff = ((size_t)b*Tt + t)*3*Cc + (size_t)h*HDd;
    float c = cos_t[((size_t)b*Tt + t)*32 + d0];
    float s = sin_t[((size_t)b*Tt + t)*32 + d0];
    float q0 = bf2f(qkv[rowoff + d0]);
    float q1 = bf2f(qkv[rowoff + d0 + 32]);
    float k0 = bf2f(qkv[rowoff + Cc + d0]);
    float k1 = bf2f(qkv[rowoff + Cc + d0 + 32]);
    float v0 = bf2f(qkv[rowoff + 2*Cc + d0]);
    float v1 = bf2f(qkv[rowoff + 2*Cc + d0 + 32]);
    float qa = q0*c - q1*s, qb = q1*c + q0*s;
    float ka = k0*c - k1*s, kb = k1*c + k0*s;
    float cs = cum[b*Tt + t];
    if (d0 == 31){ qb = 1.0f; kb = cs; }   // last dim (d=63) overwrites, post-rope
    qa *= scale; qb *= scale;              // fold softmax scale into Q
    float ev = expf(cs);
    v0 *= ev; v1 *= ev;
    size_t qrow = (((size_t)b*Hh + h)*Tt + t)*HDd;
    Q[qrow + d0]      = f2bf(qa);
    Q[qrow + d0 + 32] = f2bf(qb);
    K[qrow + d0]      = f2bf(ka);
    K[qrow + d0 + 32] = f2bf(kb);
    vt[tsub + i*8][d0]      = f2bf(v0);
    vt[tsub + i*8][d0 + 32] = f2bf(v1);
  }
  __syncthreads();
  #pragma unroll
  for (int i=0;i<16;i++){
    int d  = (threadIdx.x >> 6) + i*4;
    int ttl = threadIdx.x & 63;
    VT[(((size_t)b*Hh + h)*HDd + d)*Tt + tb + ttl] = vt[ttl][d];
  }
}

// ---------------- flash attention v5: v4 + software-pipelined loads ----------------
// K-fragments double-buffered across k-tiles (ping-pong, named buffers only);
// V-fragments issued at top of each tile's compute (first use after QK+exp).
// Load latency moves off the per-tile critical chain.
__global__ __launch_bounds__(256, 2) void k_attn5(const unsigned short* __restrict__ Q,
                                                  const unsigned short* __restrict__ K,
                                                  const unsigned short* __restrict__ VT,
                                                  unsigned short* __restrict__ Y){
  int bh = blockIdx.y; int b = bh >> 4, h = bh & 15;
  int wave = threadIdx.x>>6, lane = threadIdx.x&63;
  int lrow = lane&15, lhi = lane>>4;
  const unsigned short* Qh = Q + (((size_t)b*Hh + h)*Tt)*HDd;
  const unsigned short* Kh = K + (((size_t)b*Hh + h)*Tt)*HDd;
  const unsigned short* Vh = VT + (((size_t)b*Hh + h)*HDd)*Tt;
  int s_ = blockIdx.x;                     // 0..15
  int qL0 = 64*s_ + 16*wave;               // low strip rows
  int qH0 = 1984 - 64*s_ + 16*wave;        // mirrored high strip rows
  short8 qfL[2], qfH[2];
  qfL[0] = *(const short8*)&Qh[(size_t)(qL0+lrow)*HDd + 8*lhi];
  qfL[1] = *(const short8*)&Qh[(size_t)(qL0+lrow)*HDd + 32 + 8*lhi];
  qfH[0] = *(const short8*)&Qh[(size_t)(qH0+lrow)*HDd + 8*lhi];
  qfH[1] = *(const short8*)&Qh[(size_t)(qH0+lrow)*HDd + 32 + 8*lhi];
  f32x4 oL[4] = {}, oH[4] = {};            // [d-tile jp], rows q=4*lhi+r
  float lsL = 0.0f, lsH = 0.0f;            // per-lane l partial for q=lrow
  int rowL = qL0 + lrow, rowH = qH0 + lrow;
  int ntL = qL0/64 + 1;
  int ntH = qH0/64 + 1;

  auto LOADK = [&](short8* kf, int k0){
    #pragma unroll
    for (int j=0;j<4;j++)
      #pragma unroll
      for (int ks=0;ks<2;ks++)
        kf[2*j+ks] = *(const short8*)&Kh[(size_t)(k0 + 16*j + lrow)*HDd + 32*ks + 8*lhi];
  };
  auto COMPUTE = [&](const short8* kf, int kt){
    int k0 = kt*64;
    bool doL = (kt < ntL);
    // V loads issued FIRST: independent, consumed only after QK+exp
    short4v vf[16];
    #pragma unroll
    for (int jp=0;jp<4;jp++)
      #pragma unroll
      for (int j=0;j<4;j++)
        vf[4*jp+j] = *(const short4v*)&Vh[(size_t)(16*jp + lrow)*Tt + k0 + 16*j + 4*lhi];
    f32x4 sL[4] = {}, sH[4] = {};
    // QK^T swapped: lane = S[k=16j+4*lhi+r][q=lrow]
    #pragma unroll
    for (int j=0;j<4;j++){
      #pragma unroll
      for (int ks=0;ks<2;ks++){
        sH[j] = __builtin_amdgcn_mfma_f32_16x16x32_bf16(kf[2*j+ks], qfH[ks], sH[j], 0,0,0);
        if (doL) sL[j] = __builtin_amdgcn_mfma_f32_16x16x32_bf16(kf[2*j+ks], qfL[ks], sL[j], 0,0,0);
      }
    }
    short4v paH[4], paL[4];
    {
      bool diagH = (k0 + 63 >= qH0);
      #pragma unroll
      for (int j=0;j<4;j++){
        int kbase = k0 + 16*j + 4*lhi;
        float p0 = __expf(sH[j][0]);
        float p1 = __expf(sH[j][1]);
        float p2 = __expf(sH[j][2]);
        float p3 = __expf(sH[j][3]);
        if (diagH){
          if (kbase + 0 > rowH) p0 = 0.0f;
          if (kbase + 1 > rowH) p1 = 0.0f;
          if (kbase + 2 > rowH) p2 = 0.0f;
          if (kbase + 3 > rowH) p3 = 0.0f;
        }
        lsH += (p0 + p1) + (p2 + p3);
        union { unsigned int u[2]; short4v v; } pk;
        pk.u[0] = cvtpk_bf16(p0, p1);
        pk.u[1] = cvtpk_bf16(p2, p3);
        paH[j] = pk.v;
      }
    }
    if (doL){
      bool diagL = (k0 + 63 >= qL0);
      #pragma unroll
      for (int j=0;j<4;j++){
        int kbase = k0 + 16*j + 4*lhi;
        float p0 = __expf(sL[j][0]);
        float p1 = __expf(sL[j][1]);
        float p2 = __expf(sL[j][2]);
        float p3 = __expf(sL[j][3]);
        if (diagL){
          if (kbase + 0 > rowL) p0 = 0.0f;
          if (kbase + 1 > rowL) p1 = 0.0f;
          if (kbase + 2 > rowL) p2 = 0.0f;
          if (kbase + 3 > rowL) p3 = 0.0f;
        }
        lsL += (p0 + p1) + (p2 + p3);
        union { unsigned int u[2]; short4v v; } pk;
        pk.u[0] = cvtpk_bf16(p0, p1);
        pk.u[1] = cvtpk_bf16(p2, p3);
        paL[j] = pk.v;
      }
    }
    // PV: O[q][d] += P[q][k] V[k][d]
    #pragma unroll
    for (int jp=0;jp<4;jp++){
      #pragma unroll
      for (int j=0;j<4;j++){
        oH[jp] = mfma16(paH[j], vf[4*jp+j], oH[jp]);
        if (doL) oL[jp] = mfma16(paL[j], vf[4*jp+j], oL[jp]);
      }
    }
  };

  short8 kfA[8], kfB[8];
  LOADK(kfA, 0);
  int kt = 0;
  while (true){
    if (kt+1 < ntH) LOADK(kfB, (kt+1)*64);   // prefetch next tile's K
    COMPUTE(kfA, kt);
    if (++kt >= ntH) break;
    if (kt+1 < ntH) LOADK(kfA, (kt+1)*64);
    COMPUTE(kfB, kt);
    if (++kt >= ntH) break;
  }

  // reduce l over the 4 lane-replicas (lanes 16 apart hold same q)
  lsL += __shfl_xor(lsL, 16); lsL += __shfl_xor(lsL, 32);
  lsH += __shfl_xor(lsH, 16); lsH += __shfl_xor(lsH, 32);
  float invLl = 1.0f / lsL, invHl = 1.0f / lsH;
  float invLr[4], invHr[4];
  #pragma unroll
  for (int r=0;r<4;r++){
    invLr[r] = __shfl(invLl, 4*lhi + r);
    invHr[r] = __shfl(invHl, 4*lhi + r);
  }
  #pragma unroll
  for (int jp=0;jp<4;jp++)
    #pragma unroll
    for (int r=0;r<4;r++){
      int rqL = qL0 + 4*lhi + r;
      int rqH = qH0 + 4*lhi + r;
      int col = h*HDd + 16*jp + lrow;
      Y[((size_t)b*Tt + rqL)*Cc + col] = f2bf(oL[jp][r] * invLr[r]);
      Y[((size_t)b*Tt + rqH)*Cc + col] = f2bf(oH[jp][r] * invHr[r]);
    }
}

extern "C" void kernel_launch(void* const* d_in, const int* in_sizes, int n_in,
                              void* d_out, int out_size, void* d_ws, size_t ws_size,
                              hipStream_t stream){
  const float* x     = (const float*)d_in[0];
  const float* cum   = (const float*)d_in[1];
  const int*   tok   = (const int*)d_in[3];
  const float* Wqkv  = (const float*)d_in[4];
  const float* bqkv  = (const float*)d_in[5];
  const float* Wproj = (const float*)d_in[6];
  const float* bproj = (const float*)d_in[7];

  char* ws = (char*)d_ws;
  size_t off = 0;
  auto alloc = [&](size_t bytes)->void*{
    void* p = ws + off; off += (bytes + 255) & ~(size_t)255; return p;
  };
  unsigned short* wqkvT = (unsigned short*)alloc((size_t)3072*1024*2);
  unsigned short* wprojT= (unsigned short*)alloc((size_t)1024*1024*2);
  unsigned short* xb    = (unsigned short*)alloc((size_t)4096*1024*2); // reused as Y
  unsigned short* qkv   = (unsigned short*)alloc((size_t)4096*3072*2);
  unsigned short* Qb    = (unsigned short*)alloc((size_t)Bb*Hh*Tt*HDd*2);
  unsigned short* Kb    = (unsigned short*)alloc((size_t)Bb*Hh*Tt*HDd*2);
  unsigned short* VTb   = (unsigned short*)alloc((size_t)Bb*Hh*Tt*HDd*2);
  float* rot            = (float*)alloc((size_t)Bb*Tt*4);
  float* cos_t          = (float*)alloc((size_t)Bb*Tt*32*4);
  float* sin_t          = (float*)alloc((size_t)Bb*Tt*32*4);
  unsigned short* Y     = xb; // alias: xb dead after QKV GEMM

  k_f2b<<<dim3((4096*1024/4 + 255)/256), dim3(256), 0, stream>>>(x, xb, 4096*1024);
  k_transpose_f2b<<<dim3(3072/32, 1024/32), dim3(32,8), 0, stream>>>(Wqkv, wqkvT, 1024, 3072);
  k_transpose_f2b<<<dim3(1024/32, 1024/32), dim3(32,8), 0, stream>>>(Wproj, wprojT, 1024, 1024);
  k_scan<<<dim3(Bb), dim3(1024), 0, stream>>>(tok, rot);
  k_tables<<<dim3(Bb*Tt*32/256), dim3(256), 0, stream>>>(rot, cos_t, sin_t);
  k_gemm128<0><<<dim3(3072/128, 4096/128), dim3(256), 0, stream>>>(xb, wqkvT, bqkv, qkv, 4096, 3072, 1024);
  k_post<<<dim3(Tt/64, Hh, Bb), dim3(256), 0, stream>>>(qkv, cos_t, sin_t, cum, Qb, Kb, VTb);
  k_attn5<<<dim3(16, Bb*Hh), dim3(256), 0, stream>>>(Qb, Kb, VTb, Y);
  k_gemm128<1><<<dim3(1024/128, 4096/128), dim3(256), 0, stream>>>(Y, wprojT, bproj, (float*)d_out, 4096, 1024, 1024);
}

// Round 6
// 158.586 us; speedup vs baseline: 1.9164x; 1.6873x over previous
//
#include <hip/hip_runtime.h>
#include <hip/hip_bf16.h>
#include <math.h>

#define Bb 2
#define Tt 2048
#define Cc 1024
#define Hh 16
#define HDd 64

typedef __attribute__((ext_vector_type(8))) short short8;
typedef __attribute__((ext_vector_type(4))) short short4v;
typedef __attribute__((ext_vector_type(4))) float f32x4;

#if defined(__has_builtin)
#if __has_builtin(__builtin_amdgcn_global_load_lds)
#define USE_GLL 1
#endif
#endif
#define AS_GLOBAL __attribute__((address_space(1)))
#define AS_LDS    __attribute__((address_space(3)))

__device__ __forceinline__ float bf2f(unsigned short u){
  union { unsigned int i; float f; } v; v.i = ((unsigned int)u)<<16; return v.f;
}
__device__ __forceinline__ unsigned short f2bf(float f){
  union { float f; unsigned int i; } v; v.f = f;
  unsigned int x = v.i;
  return (unsigned short)((x + 0x7fffu + ((x>>16)&1u)) >> 16);
}
__device__ __forceinline__ unsigned int cvtpk_bf16(float lo, float hi){
  unsigned int r;
  asm("v_cvt_pk_bf16_f32 %0, %1, %2" : "=v"(r) : "v"(lo), "v"(hi));
  return r;
}
__device__ __forceinline__ f32x4 mfma16(short4v a, short4v b, f32x4 c){
#if defined(__has_builtin)
#if __has_builtin(__builtin_amdgcn_mfma_f32_16x16x16_bf16)
  return __builtin_amdgcn_mfma_f32_16x16x16_bf16(a, b, c, 0, 0, 0);
#elif __has_builtin(__builtin_amdgcn_mfma_f32_16x16x16bf16_1k)
  return __builtin_amdgcn_mfma_f32_16x16x16bf16_1k(a, b, c, 0, 0, 0);
#else
  asm("v_mfma_f32_16x16x16_bf16 %0, %1, %2, %3" : "=v"(c) : "v"(a), "v"(b), "0"(c));
  return c;
#endif
#else
  asm("v_mfma_f32_16x16x16_bf16 %0, %1, %2, %3" : "=v"(c) : "v"(a), "v"(b), "0"(c));
  return c;
#endif
}

// ---------------- fp32 -> bf16 convert (vector) ----------------
__global__ __launch_bounds__(256) void k_f2b(const float* __restrict__ in,
                                             unsigned short* __restrict__ out, int n){
  int i = (blockIdx.x*256 + threadIdx.x)*4;
  if (i >= n) return;
  float4 v = *(const float4*)(in + i);
  unsigned long long p = (unsigned long long)f2bf(v.x)
                       | ((unsigned long long)f2bf(v.y)<<16)
                       | ((unsigned long long)f2bf(v.z)<<32)
                       | ((unsigned long long)f2bf(v.w)<<48);
  *(unsigned long long*)(out + i) = p;
}

// ---------------- transpose + convert: W[K][N] f32 -> Wt[N][K] bf16 ----------------
__global__ __launch_bounds__(256) void k_transpose_f2b(const float* __restrict__ in,
                                                       unsigned short* __restrict__ out,
                                                       int K, int N){
  __shared__ float tile[32][33];
  int kb = blockIdx.y*32, nb = blockIdx.x*32;
  int tx = threadIdx.x, ty = threadIdx.y; // (32, 8)
  #pragma unroll
  for (int i=0;i<4;i++)
    tile[ty+i*8][tx] = in[(size_t)(kb+ty+i*8)*N + nb + tx];
  __syncthreads();
  #pragma unroll
  for (int i=0;i<4;i++)
    out[(size_t)(nb+ty+i*8)*K + kb + tx] = f2bf(tile[tx][ty+i*8]);
}

// ---------------- scan: global token counts -> per-batch cumulative rotations ----------------
__global__ __launch_bounds__(1024) void k_scan(const int* __restrict__ tok,
                                               float* __restrict__ rot){
  __shared__ int cnt[2048];
  __shared__ float vals[2048];
  __shared__ float psum[1024];
  int b = blockIdx.x;
  int tid = threadIdx.x;
  cnt[tid] = 0; cnt[tid+1024] = 0;
  __syncthreads();
  // reference's fancy-indexing scatters ALL batches' tokens into every batch's counts
  for (int i = tid; i < Bb*Tt; i += 1024) atomicAdd(&cnt[tok[i]], 1);
  __syncthreads();
  for (int i = tid; i < Tt; i += 1024){
    int idx = tok[b*Tt + i];
    vals[i] = 1.0f / ((float)cnt[idx] + 1e-10f);
  }
  __syncthreads();
  float s0 = vals[2*tid], s1 = vals[2*tid+1];
  psum[tid] = s0 + s1;
  __syncthreads();
  for (int off=1; off<1024; off<<=1){
    float add = (tid>=off) ? psum[tid-off] : 0.0f;
    __syncthreads();
    psum[tid] += add;
    __syncthreads();
  }
  float base = (tid>0) ? psum[tid-1] : 0.0f;
  rot[b*Tt + 2*tid]   = base + s0;
  rot[b*Tt + 2*tid+1] = base + s0 + s1;
}

// ---------------- cos/sin tables from rotations ----------------
__global__ __launch_bounds__(256) void k_tables(const float* __restrict__ rot,
                                                float* __restrict__ cos_t,
                                                float* __restrict__ sin_t){
  int i = blockIdx.x*256 + threadIdx.x;   // over Bb*Tt*32
  int j = i & 31;
  int bt = i >> 5;
  float invf = exp2f(-(float)j * 0.4152410118609203f);  // 10000^(-j/32)
  float ang = rot[bt] * invf;
  cos_t[i] = cosf(ang);
  sin_t[i] = sinf(ang);
}

// ---------------- 128x128-tile bf16 MFMA GEMM: C = A[M][K] @ Bt[N][K]^T + bias ----------------
template<int OUTF32>
__global__ __launch_bounds__(256) void k_gemm128(const unsigned short* __restrict__ A,
                                                 const unsigned short* __restrict__ Bt,
                                                 const float* __restrict__ bias,
                                                 void* __restrict__ Cout,
                                                 int M, int N, int K){
  __shared__ unsigned short As[128][32];
  __shared__ unsigned short Bs[128][32];
  int mb = blockIdx.y*128, nb = blockIdx.x*128;
  int tid = threadIdx.x;
  int wave = tid>>6, lane = tid&63;
  int wr = wave>>1, wc = wave&1;
  int lrow = lane&15, lhi = lane>>4;
  f32x4 acc[4][4] = {};
  int r0 = tid>>2;          // 0..63 (rows r0 and r0+64)
  int c0 = (tid&3)*8;       // 16B column group
  const unsigned short* Arow0 = A  + (size_t)(mb + r0)*K      + c0;
  const unsigned short* Arow1 = A  + (size_t)(mb + r0 + 64)*K + c0;
  const unsigned short* Brow0 = Bt + (size_t)(nb + r0)*K      + c0;
  const unsigned short* Brow1 = Bt + (size_t)(nb + r0 + 64)*K + c0;
#ifdef USE_GLL
  for (int kb=0; kb<K; kb+=32){
    __builtin_amdgcn_global_load_lds((const AS_GLOBAL void*)(Arow0 + kb),
                                     (AS_LDS void*)&As[r0][c0],    16, 0, 0);
    __builtin_amdgcn_global_load_lds((const AS_GLOBAL void*)(Arow1 + kb),
                                     (AS_LDS void*)&As[r0+64][c0], 16, 0, 0);
    __builtin_amdgcn_global_load_lds((const AS_GLOBAL void*)(Brow0 + kb),
                                     (AS_LDS void*)&Bs[r0][c0],    16, 0, 0);
    __builtin_amdgcn_global_load_lds((const AS_GLOBAL void*)(Brow1 + kb),
                                     (AS_LDS void*)&Bs[r0+64][c0], 16, 0, 0);
    __syncthreads();
    short8 af[4], bf[4];
    #pragma unroll
    for (int m=0;m<4;m++) af[m] = *(const short8*)&As[64*wr + 16*m + lrow][8*lhi];
    #pragma unroll
    for (int n=0;n<4;n++) bf[n] = *(const short8*)&Bs[64*wc + 16*n + lrow][8*lhi];
    #pragma unroll
    for (int m=0;m<4;m++)
      #pragma unroll
      for (int n=0;n<4;n++)
        acc[m][n] = __builtin_amdgcn_mfma_f32_16x16x32_bf16(af[m], bf[n], acc[m][n], 0,0,0);
    __syncthreads();
  }
#else
  for (int kb=0; kb<K; kb+=32){
    int4 a0 = *(const int4*)(Arow0 + kb);
    int4 a1 = *(const int4*)(Arow1 + kb);
    int4 b0 = *(const int4*)(Brow0 + kb);
    int4 b1 = *(const int4*)(Brow1 + kb);
    __syncthreads();
    *(int4*)&As[r0][c0]    = a0;
    *(int4*)&As[r0+64][c0] = a1;
    *(int4*)&Bs[r0][c0]    = b0;
    *(int4*)&Bs[r0+64][c0] = b1;
    __syncthreads();
    short8 af[4], bf[4];
    #pragma unroll
    for (int m=0;m<4;m++) af[m] = *(const short8*)&As[64*wr + 16*m + lrow][8*lhi];
    #pragma unroll
    for (int n=0;n<4;n++) bf[n] = *(const short8*)&Bs[64*wc + 16*n + lrow][8*lhi];
    #pragma unroll
    for (int m=0;m<4;m++)
      #pragma unroll
      for (int n=0;n<4;n++)
        acc[m][n] = __builtin_amdgcn_mfma_f32_16x16x32_bf16(af[m], bf[n], acc[m][n], 0,0,0);
  }
#endif
  #pragma unroll
  for (int m=0;m<4;m++)
    #pragma unroll
    for (int n=0;n<4;n++)
      #pragma unroll
      for (int q=0;q<4;q++){
        int row = mb + 64*wr + 16*m + 4*lhi + q;
        int col = nb + 64*wc + 16*n + lrow;
        float v = acc[m][n][q] + bias[col];
        if (OUTF32) ((float*)Cout)[(size_t)row*N + col] = v;
        else ((unsigned short*)Cout)[(size_t)row*N + col] = f2bf(v);
      }
}

// ---------------- post-QKV: rope, overwrites, v-scale; write Q,K,[VT transposed] ----------------
__global__ __launch_bounds__(256) void k_post(const unsigned short* __restrict__ qkv,
                                              const float* __restrict__ cos_t,
                                              const float* __restrict__ sin_t,
                                              const float* __restrict__ cum,
                                              unsigned short* __restrict__ Q,
                                              unsigned short* __restrict__ K,
                                              unsigned short* __restrict__ VT){
  __shared__ unsigned short vt[64][66];
  int b = blockIdx.z, h = blockIdx.y, tb = blockIdx.x*64;
  int d0 = threadIdx.x & 31, tsub = threadIdx.x >> 5; // 32 x 8
  const float scale = 0.125f;
  #pragma unroll
  for (int i=0;i<8;i++){
    int t = tb + tsub + i*8;
    size_t rowoff = ((size_t)b*Tt + t)*3*Cc + (size_t)h*HDd;
    float c = cos_t[((size_t)b*Tt + t)*32 + d0];
    float s = sin_t[((size_t)b*Tt + t)*32 + d0];
    float q0 = bf2f(qkv[rowoff + d0]);
    float q1 = bf2f(qkv[rowoff + d0 + 32]);
    float k0 = bf2f(qkv[rowoff + Cc + d0]);
    float k1 = bf2f(qkv[rowoff + Cc + d0 + 32]);
    float v0 = bf2f(qkv[rowoff + 2*Cc + d0]);
    float v1 = bf2f(qkv[rowoff + 2*Cc + d0 + 32]);
    float qa = q0*c - q1*s, qb = q1*c + q0*s;
    float ka = k0*c - k1*s, kb = k1*c + k0*s;
    float cs = cum[b*Tt + t];
    if (d0 == 31){ qb = 1.0f; kb = cs; }   // last dim (d=63) overwrites, post-rope
    qa *= scale; qb *= scale;              // fold softmax scale into Q
    float ev = expf(cs);
    v0 *= ev; v1 *= ev;
    size_t qrow = (((size_t)b*Hh + h)*Tt + t)*HDd;
    Q[qrow + d0]      = f2bf(qa);
    Q[qrow + d0 + 32] = f2bf(qb);
    K[qrow + d0]      = f2bf(ka);
    K[qrow + d0 + 32] = f2bf(kb);
    vt[tsub + i*8][d0]      = f2bf(v0);
    vt[tsub + i*8][d0 + 32] = f2bf(v1);
  }
  __syncthreads();
  #pragma unroll
  for (int i=0;i<16;i++){
    int d  = (threadIdx.x >> 6) + i*4;
    int ttl = threadIdx.x & 63;
    VT[(((size_t)b*Hh + h)*HDd + d)*Tt + tb + ttl] = vt[ttl][d];
  }
}

// ---------------- flash attention v6: LDS-staged K/V (global_load_lds dbuf) ----------------
// 4 waves/block share each 64x64 K-tile and V-tile staged via global_load_lds.
// LDS holds XOR-swizzled data: linear dest + inverse-swizzled GLOBAL source,
// reads apply byte16group ^= (row&7). P stays in-register (swapped-QK layout).
// Fixed m=0 softmax; l per-lane partial, reduced once at end.
__global__ __launch_bounds__(256, 2) void k_attn6(const unsigned short* __restrict__ Q,
                                                  const unsigned short* __restrict__ K,
                                                  const unsigned short* __restrict__ VT,
                                                  unsigned short* __restrict__ Y){
  __shared__ unsigned short Ks[2][64*64];
  __shared__ unsigned short Vs[2][64*64];
  int bh = blockIdx.y; int b = bh >> 4, h = bh & 15;
  int tid = threadIdx.x;
  int wave = tid>>6, lane = tid&63;
  int lrow = lane&15, lhi = lane>>4;
  const unsigned short* Qh = Q + (((size_t)b*Hh + h)*Tt)*HDd;
  const unsigned short* Kh = K + (((size_t)b*Hh + h)*Tt)*HDd;
  const unsigned short* Vh = VT + (((size_t)b*Hh + h)*HDd)*Tt;
  int s_ = blockIdx.x;                     // 0..15
  int qL0 = 64*s_ + 16*wave;               // low strip rows
  int qH0 = 1984 - 64*s_ + 16*wave;        // mirrored high strip rows
  short8 qfL0 = *(const short8*)&Qh[(size_t)(qL0+lrow)*HDd + 8*lhi];
  short8 qfL1 = *(const short8*)&Qh[(size_t)(qL0+lrow)*HDd + 32 + 8*lhi];
  short8 qfH0 = *(const short8*)&Qh[(size_t)(qH0+lrow)*HDd + 8*lhi];
  short8 qfH1 = *(const short8*)&Qh[(size_t)(qH0+lrow)*HDd + 32 + 8*lhi];
  f32x4 oL[4] = {}, oH[4] = {};            // [d-tile jp], rows q=4*lhi+r
  float lsL = 0.0f, lsH = 0.0f;            // per-lane l partial for q=lrow
  int rowL = qL0 + lrow, rowH = qH0 + lrow;
  int ntL = qL0/64 + 1;                    // = s_+1  (uniform over waves)
  int ntH = qH0/64 + 1;                    // = 32-s_ (uniform over waves)

  // staging geometry: two 16B rounds per tile per thread (8KB tile / 256 thr / 16B)
  // linear LDS byte o -> row = o>>7, col16 = (o>>4)&7; swizzled source col16^(row&7)
  int o0 = tid*16, o1 = (tid+256)*16;
  int kr0 = o0>>7, kc0 = (o0>>4)&7;
  int kr1 = o1>>7, kc1 = (o1>>4)&7;
  int ksrc0 = kr0*HDd + ((kc0^(kr0&7))<<3);
  int ksrc1 = kr1*HDd + ((kc1^(kr1&7))<<3);
  int vsrc0 = kr0*Tt + ((kc0^(kr0&7))<<3);
  int vsrc1 = kr1*Tt + ((kc1^(kr1&7))<<3);

#ifdef USE_GLL
#define STAGE(bufi, k0_) do { \
    __builtin_amdgcn_global_load_lds((const AS_GLOBAL void*)(Kh + (size_t)(k0_)*HDd + ksrc0), \
        (AS_LDS void*)((AS_LDS char*)&Ks[bufi][0] + o0), 16, 0, 0); \
    __builtin_amdgcn_global_load_lds((const AS_GLOBAL void*)(Kh + (size_t)(k0_)*HDd + ksrc1), \
        (AS_LDS void*)((AS_LDS char*)&Ks[bufi][0] + o1), 16, 0, 0); \
    __builtin_amdgcn_global_load_lds((const AS_GLOBAL void*)(Vh + (size_t)(k0_) + vsrc0), \
        (AS_LDS void*)((AS_LDS char*)&Vs[bufi][0] + o0), 16, 0, 0); \
    __builtin_amdgcn_global_load_lds((const AS_GLOBAL void*)(Vh + (size_t)(k0_) + vsrc1), \
        (AS_LDS void*)((AS_LDS char*)&Vs[bufi][0] + o1), 16, 0, 0); \
  } while(0)
#else
#define STAGE(bufi, k0_) do { \
    int4 a_ = *(const int4*)(Kh + (size_t)(k0_)*HDd + ksrc0); \
    int4 b_ = *(const int4*)(Kh + (size_t)(k0_)*HDd + ksrc1); \
    int4 c_ = *(const int4*)(Vh + (size_t)(k0_) + vsrc0); \
    int4 d_ = *(const int4*)(Vh + (size_t)(k0_) + vsrc1); \
    *(int4*)((char*)&Ks[bufi][0] + o0) = a_; \
    *(int4*)((char*)&Ks[bufi][0] + o1) = b_; \
    *(int4*)((char*)&Vs[bufi][0] + o0) = c_; \
    *(int4*)((char*)&Vs[bufi][0] + o1) = d_; \
  } while(0)
#endif

  STAGE(0, 0);
  int buf = 0;
  for (int kt = 0; kt < ntH; kt++){
    int k0 = kt*64;
    bool doL = (kt < ntL);
    __syncthreads();                       // staging of buf complete
    if (kt+1 < ntH) STAGE(buf^1, (kt+1)*64);

    // --- K fragments from LDS (swizzled) + QK^T (swapped operands) ---
    f32x4 sL[4] = {}, sH[4] = {};
    #pragma unroll
    for (int j=0;j<4;j++){
      int krow = 16*j + lrow;
      #pragma unroll
      for (int ks=0;ks<2;ks++){
        int dgrp = (4*ks + lhi) ^ (krow&7);
        short8 kf = *(const short8*)&Ks[buf][krow*64 + dgrp*8];
        sH[j] = __builtin_amdgcn_mfma_f32_16x16x32_bf16(kf, ks ? qfH1 : qfH0, sH[j], 0,0,0);
        if (doL) sL[j] = __builtin_amdgcn_mfma_f32_16x16x32_bf16(kf, ks ? qfL1 : qfL0, sL[j], 0,0,0);
      }
    }
    // --- exp + in-lane pack to PV A-fragments ---
    short4v paH[4], paL[4];
    {
      bool diagH = (k0 + 63 >= qH0);
      #pragma unroll
      for (int j=0;j<4;j++){
        int kbase = k0 + 16*j + 4*lhi;
        float p0 = __expf(sH[j][0]);
        float p1 = __expf(sH[j][1]);
        float p2 = __expf(sH[j][2]);
        float p3 = __expf(sH[j][3]);
        if (diagH){
          if (kbase + 0 > rowH) p0 = 0.0f;
          if (kbase + 1 > rowH) p1 = 0.0f;
          if (kbase + 2 > rowH) p2 = 0.0f;
          if (kbase + 3 > rowH) p3 = 0.0f;
        }
        lsH += (p0 + p1) + (p2 + p3);
        union { unsigned int u[2]; short4v v; } pk;
        pk.u[0] = cvtpk_bf16(p0, p1);
        pk.u[1] = cvtpk_bf16(p2, p3);
        paH[j] = pk.v;
      }
    }
    if (doL){
      bool diagL = (k0 + 63 >= qL0);
      #pragma unroll
      for (int j=0;j<4;j++){
        int kbase = k0 + 16*j + 4*lhi;
        float p0 = __expf(sL[j][0]);
        float p1 = __expf(sL[j][1]);
        float p2 = __expf(sL[j][2]);
        float p3 = __expf(sL[j][3]);
        if (diagL){
          if (kbase + 0 > rowL) p0 = 0.0f;
          if (kbase + 1 > rowL) p1 = 0.0f;
          if (kbase + 2 > rowL) p2 = 0.0f;
          if (kbase + 3 > rowL) p3 = 0.0f;
        }
        lsL += (p0 + p1) + (p2 + p3);
        union { unsigned int u[2]; short4v v; } pk;
        pk.u[0] = cvtpk_bf16(p0, p1);
        pk.u[1] = cvtpk_bf16(p2, p3);
        paL[j] = pk.v;
      }
    }
    // --- PV from LDS V (swizzled b64 reads): O[q][d] += P[q][k] V[k][d] ---
    #pragma unroll
    for (int jp=0;jp<4;jp++){
      int vrow = 16*jp + lrow;
      #pragma unroll
      for (int j=0;j<4;j++){
        int byte_in_row = ((((2*j + (lhi>>1)) ^ (vrow&7)) << 4) | ((lhi&1) << 3));
        short4v vf = *(const short4v*)((const char*)&Vs[buf][vrow*64] + byte_in_row);
        oH[jp] = mfma16(paH[j], vf, oH[jp]);
        if (doL) oL[jp] = mfma16(paL[j], vf, oL[jp]);
      }
    }
    buf ^= 1;
  }

  // reduce l over the 4 lane-replicas (lanes 16 apart hold same q)
  lsL += __shfl_xor(lsL, 16); lsL += __shfl_xor(lsL, 32);
  lsH += __shfl_xor(lsH, 16); lsH += __shfl_xor(lsH, 32);
  float invLl = 1.0f / lsL, invHl = 1.0f / lsH;
  float invLr[4], invHr[4];
  #pragma unroll
  for (int r=0;r<4;r++){
    invLr[r] = __shfl(invLl, 4*lhi + r);
    invHr[r] = __shfl(invHl, 4*lhi + r);
  }
  #pragma unroll
  for (int jp=0;jp<4;jp++)
    #pragma unroll
    for (int r=0;r<4;r++){
      int rqL = qL0 + 4*lhi + r;
      int rqH = qH0 + 4*lhi + r;
      int col = h*HDd + 16*jp + lrow;
      Y[((size_t)b*Tt + rqL)*Cc + col] = f2bf(oL[jp][r] * invLr[r]);
      Y[((size_t)b*Tt + rqH)*Cc + col] = f2bf(oH[jp][r] * invHr[r]);
    }
#undef STAGE
}

extern "C" void kernel_launch(void* const* d_in, const int* in_sizes, int n_in,
                              void* d_out, int out_size, void* d_ws, size_t ws_size,
                              hipStream_t stream){
  const float* x     = (const float*)d_in[0];
  const float* cum   = (const float*)d_in[1];
  const int*   tok   = (const int*)d_in[3];
  const float* Wqkv  = (const float*)d_in[4];
  const float* bqkv  = (const float*)d_in[5];
  const float* Wproj = (const float*)d_in[6];
  const float* bproj = (const float*)d_in[7];

  char* ws = (char*)d_ws;
  size_t off = 0;
  auto alloc = [&](size_t bytes)->void*{
    void* p = ws + off; off += (bytes + 255) & ~(size_t)255; return p;
  };
  unsigned short* wqkvT = (unsigned short*)alloc((size_t)3072*1024*2);
  unsigned short* wprojT= (unsigned short*)alloc((size_t)1024*1024*2);
  unsigned short* xb    = (unsigned short*)alloc((size_t)4096*1024*2); // reused as Y
  unsigned short* qkv   = (unsigned short*)alloc((size_t)4096*3072*2);
  unsigned short* Qb    = (unsigned short*)alloc((size_t)Bb*Hh*Tt*HDd*2);
  unsigned short* Kb    = (unsigned short*)alloc((size_t)Bb*Hh*Tt*HDd*2);
  unsigned short* VTb   = (unsigned short*)alloc((size_t)Bb*Hh*Tt*HDd*2);
  float* rot            = (float*)alloc((size_t)Bb*Tt*4);
  float* cos_t          = (float*)alloc((size_t)Bb*Tt*32*4);
  float* sin_t          = (float*)alloc((size_t)Bb*Tt*32*4);
  unsigned short* Y     = xb; // alias: xb dead after QKV GEMM

  k_f2b<<<dim3((4096*1024/4 + 255)/256), dim3(256), 0, stream>>>(x, xb, 4096*1024);
  k_transpose_f2b<<<dim3(3072/32, 1024/32), dim3(32,8), 0, stream>>>(Wqkv, wqkvT, 1024, 3072);
  k_transpose_f2b<<<dim3(1024/32, 1024/32), dim3(32,8), 0, stream>>>(Wproj, wprojT, 1024, 1024);
  k_scan<<<dim3(Bb), dim3(1024), 0, stream>>>(tok, rot);
  k_tables<<<dim3(Bb*Tt*32/256), dim3(256), 0, stream>>>(rot, cos_t, sin_t);
  k_gemm128<0><<<dim3(3072/128, 4096/128), dim3(256), 0, stream>>>(xb, wqkvT, bqkv, qkv, 4096, 3072, 1024);
  k_post<<<dim3(Tt/64, Hh, Bb), dim3(256), 0, stream>>>(qkv, cos_t, sin_t, cum, Qb, Kb, VTb);
  k_attn6<<<dim3(16, Bb*Hh), dim3(256), 0, stream>>>(Qb, Kb, VTb, Y);
  k_gemm128<1><<<dim3(1024/128, 4096/128), dim3(256), 0, stream>>>(Y, wprojT, bproj, (float*)d_out, 4096, 1024, 1024);
}

// Round 7
// 131.537 us; speedup vs baseline: 2.3104x; 1.2056x over previous
//
#include <hip/hip_runtime.h>
#include <hip/hip_bf16.h>
#include <math.h>

#define Bb 2
#define Tt 2048
#define Cc 1024
#define Hh 16
#define HDd 64

typedef __attribute__((ext_vector_type(8))) short short8;
typedef __attribute__((ext_vector_type(4))) short short4v;
typedef __attribute__((ext_vector_type(4))) float f32x4;

#if defined(__has_builtin)
#if __has_builtin(__builtin_amdgcn_global_load_lds)
#define USE_GLL 1
#endif
#endif
#define AS_GLOBAL __attribute__((address_space(1)))
#define AS_LDS    __attribute__((address_space(3)))

__device__ __forceinline__ float bf2f(unsigned short u){
  union { unsigned int i; float f; } v; v.i = ((unsigned int)u)<<16; return v.f;
}
__device__ __forceinline__ unsigned short f2bf(float f){
  union { float f; unsigned int i; } v; v.f = f;
  unsigned int x = v.i;
  return (unsigned short)((x + 0x7fffu + ((x>>16)&1u)) >> 16);
}
__device__ __forceinline__ unsigned int cvtpk_bf16(float lo, float hi){
  unsigned int r;
  asm("v_cvt_pk_bf16_f32 %0, %1, %2" : "=v"(r) : "v"(lo), "v"(hi));
  return r;
}
__device__ __forceinline__ f32x4 mfma16(short4v a, short4v b, f32x4 c){
#if defined(__has_builtin)
#if __has_builtin(__builtin_amdgcn_mfma_f32_16x16x16_bf16)
  return __builtin_amdgcn_mfma_f32_16x16x16_bf16(a, b, c, 0, 0, 0);
#elif __has_builtin(__builtin_amdgcn_mfma_f32_16x16x16bf16_1k)
  return __builtin_amdgcn_mfma_f32_16x16x16bf16_1k(a, b, c, 0, 0, 0);
#else
  asm("v_mfma_f32_16x16x16_bf16 %0, %1, %2, %3" : "=v"(c) : "v"(a), "v"(b), "0"(c));
  return c;
#endif
#else
  asm("v_mfma_f32_16x16x16_bf16 %0, %1, %2, %3" : "=v"(c) : "v"(a), "v"(b), "0"(c));
  return c;
#endif
}

// ---------------- fp32 -> bf16 convert (vector) ----------------
__global__ __launch_bounds__(256) void k_f2b(const float* __restrict__ in,
                                             unsigned short* __restrict__ out, int n){
  int i = (blockIdx.x*256 + threadIdx.x)*4;
  if (i >= n) return;
  float4 v = *(const float4*)(in + i);
  unsigned long long p = (unsigned long long)f2bf(v.x)
                       | ((unsigned long long)f2bf(v.y)<<16)
                       | ((unsigned long long)f2bf(v.z)<<32)
                       | ((unsigned long long)f2bf(v.w)<<48);
  *(unsigned long long*)(out + i) = p;
}

// ---------------- transpose + convert: W[K][N] f32 -> Wt[N][K] bf16 ----------------
__global__ __launch_bounds__(256) void k_transpose_f2b(const float* __restrict__ in,
                                                       unsigned short* __restrict__ out,
                                                       int K, int N){
  __shared__ float tile[32][33];
  int kb = blockIdx.y*32, nb = blockIdx.x*32;
  int tx = threadIdx.x, ty = threadIdx.y; // (32, 8)
  #pragma unroll
  for (int i=0;i<4;i++)
    tile[ty+i*8][tx] = in[(size_t)(kb+ty+i*8)*N + nb + tx];
  __syncthreads();
  #pragma unroll
  for (int i=0;i<4;i++)
    out[(size_t)(nb+ty+i*8)*K + kb + tx] = f2bf(tile[tx][ty+i*8]);
}

// ---------------- scan: global token counts -> per-batch cumulative rotations ----------------
__global__ __launch_bounds__(1024) void k_scan(const int* __restrict__ tok,
                                               float* __restrict__ rot){
  __shared__ int cnt[2048];
  __shared__ float vals[2048];
  __shared__ float psum[1024];
  int b = blockIdx.x;
  int tid = threadIdx.x;
  cnt[tid] = 0; cnt[tid+1024] = 0;
  __syncthreads();
  // reference's fancy-indexing scatters ALL batches' tokens into every batch's counts
  for (int i = tid; i < Bb*Tt; i += 1024) atomicAdd(&cnt[tok[i]], 1);
  __syncthreads();
  for (int i = tid; i < Tt; i += 1024){
    int idx = tok[b*Tt + i];
    vals[i] = 1.0f / ((float)cnt[idx] + 1e-10f);
  }
  __syncthreads();
  float s0 = vals[2*tid], s1 = vals[2*tid+1];
  psum[tid] = s0 + s1;
  __syncthreads();
  for (int off=1; off<1024; off<<=1){
    float add = (tid>=off) ? psum[tid-off] : 0.0f;
    __syncthreads();
    psum[tid] += add;
    __syncthreads();
  }
  float base = (tid>0) ? psum[tid-1] : 0.0f;
  rot[b*Tt + 2*tid]   = base + s0;
  rot[b*Tt + 2*tid+1] = base + s0 + s1;
}

// ---------------- cos/sin tables from rotations ----------------
__global__ __launch_bounds__(256) void k_tables(const float* __restrict__ rot,
                                                float* __restrict__ cos_t,
                                                float* __restrict__ sin_t){
  int i = blockIdx.x*256 + threadIdx.x;   // over Bb*Tt*32
  int j = i & 31;
  int bt = i >> 5;
  float invf = exp2f(-(float)j * 0.4152410118609203f);  // 10000^(-j/32)
  float ang = rot[bt] * invf;
  cos_t[i] = cosf(ang);
  sin_t[i] = sinf(ang);
}

// ---------------- 128x128-tile bf16 MFMA GEMM: C = A[M][K] @ Bt[N][K]^T + bias ----------------
template<int OUTF32>
__global__ __launch_bounds__(256) void k_gemm128(const unsigned short* __restrict__ A,
                                                 const unsigned short* __restrict__ Bt,
                                                 const float* __restrict__ bias,
                                                 void* __restrict__ Cout,
                                                 int M, int N, int K){
  __shared__ unsigned short As[128][32];
  __shared__ unsigned short Bs[128][32];
  int mb = blockIdx.y*128, nb = blockIdx.x*128;
  int tid = threadIdx.x;
  int wave = tid>>6, lane = tid&63;
  int wr = wave>>1, wc = wave&1;
  int lrow = lane&15, lhi = lane>>4;
  f32x4 acc[4][4] = {};
  int r0 = tid>>2;          // 0..63 (rows r0 and r0+64)
  int c0 = (tid&3)*8;       // 16B column group
  const unsigned short* Arow0 = A  + (size_t)(mb + r0)*K      + c0;
  const unsigned short* Arow1 = A  + (size_t)(mb + r0 + 64)*K + c0;
  const unsigned short* Brow0 = Bt + (size_t)(nb + r0)*K      + c0;
  const unsigned short* Brow1 = Bt + (size_t)(nb + r0 + 64)*K + c0;
#ifdef USE_GLL
  for (int kb=0; kb<K; kb+=32){
    __builtin_amdgcn_global_load_lds((const AS_GLOBAL void*)(Arow0 + kb),
                                     (AS_LDS void*)&As[r0][c0],    16, 0, 0);
    __builtin_amdgcn_global_load_lds((const AS_GLOBAL void*)(Arow1 + kb),
                                     (AS_LDS void*)&As[r0+64][c0], 16, 0, 0);
    __builtin_amdgcn_global_load_lds((const AS_GLOBAL void*)(Brow0 + kb),
                                     (AS_LDS void*)&Bs[r0][c0],    16, 0, 0);
    __builtin_amdgcn_global_load_lds((const AS_GLOBAL void*)(Brow1 + kb),
                                     (AS_LDS void*)&Bs[r0+64][c0], 16, 0, 0);
    __syncthreads();
    short8 af[4], bf[4];
    #pragma unroll
    for (int m=0;m<4;m++) af[m] = *(const short8*)&As[64*wr + 16*m + lrow][8*lhi];
    #pragma unroll
    for (int n=0;n<4;n++) bf[n] = *(const short8*)&Bs[64*wc + 16*n + lrow][8*lhi];
    #pragma unroll
    for (int m=0;m<4;m++)
      #pragma unroll
      for (int n=0;n<4;n++)
        acc[m][n] = __builtin_amdgcn_mfma_f32_16x16x32_bf16(af[m], bf[n], acc[m][n], 0,0,0);
    __syncthreads();
  }
#else
  for (int kb=0; kb<K; kb+=32){
    int4 a0 = *(const int4*)(Arow0 + kb);
    int4 a1 = *(const int4*)(Arow1 + kb);
    int4 b0 = *(const int4*)(Brow0 + kb);
    int4 b1 = *(const int4*)(Brow1 + kb);
    __syncthreads();
    *(int4*)&As[r0][c0]    = a0;
    *(int4*)&As[r0+64][c0] = a1;
    *(int4*)&Bs[r0][c0]    = b0;
    *(int4*)&Bs[r0+64][c0] = b1;
    __syncthreads();
    short8 af[4], bf[4];
    #pragma unroll
    for (int m=0;m<4;m++) af[m] = *(const short8*)&As[64*wr + 16*m + lrow][8*lhi];
    #pragma unroll
    for (int n=0;n<4;n++) bf[n] = *(const short8*)&Bs[64*wc + 16*n + lrow][8*lhi];
    #pragma unroll
    for (int m=0;m<4;m++)
      #pragma unroll
      for (int n=0;n<4;n++)
        acc[m][n] = __builtin_amdgcn_mfma_f32_16x16x32_bf16(af[m], bf[n], acc[m][n], 0,0,0);
  }
#endif
  #pragma unroll
  for (int m=0;m<4;m++)
    #pragma unroll
    for (int n=0;n<4;n++)
      #pragma unroll
      for (int q=0;q<4;q++){
        int row = mb + 64*wr + 16*m + 4*lhi + q;
        int col = nb + 64*wc + 16*n + lrow;
        float v = acc[m][n][q] + bias[col];
        if (OUTF32) ((float*)Cout)[(size_t)row*N + col] = v;
        else ((unsigned short*)Cout)[(size_t)row*N + col] = f2bf(v);
      }
}

// ---------------- 64x128-tile GEMM (fp32 out) for proj: 2 blocks/CU occupancy ----------------
__global__ __launch_bounds__(256) void k_gemm64(const unsigned short* __restrict__ A,
                                                const unsigned short* __restrict__ Bt,
                                                const float* __restrict__ bias,
                                                float* __restrict__ Cout,
                                                int M, int N, int K){
  __shared__ unsigned short As[64][32];
  __shared__ unsigned short Bs[128][32];
  int mb = blockIdx.y*64, nb = blockIdx.x*128;
  int tid = threadIdx.x;
  int wave = tid>>6, lane = tid&63;
  int wr = wave>>1, wc = wave&1;
  int lrow = lane&15, lhi = lane>>4;
  f32x4 acc[2][4] = {};
  int r0 = tid>>2;          // 0..63
  int c0 = (tid&3)*8;
  const unsigned short* Arow  = A  + (size_t)(mb + r0)*K      + c0;
  const unsigned short* Brow0 = Bt + (size_t)(nb + r0)*K      + c0;
  const unsigned short* Brow1 = Bt + (size_t)(nb + r0 + 64)*K + c0;
#ifdef USE_GLL
  for (int kb=0; kb<K; kb+=32){
    __builtin_amdgcn_global_load_lds((const AS_GLOBAL void*)(Arow + kb),
                                     (AS_LDS void*)&As[r0][c0],    16, 0, 0);
    __builtin_amdgcn_global_load_lds((const AS_GLOBAL void*)(Brow0 + kb),
                                     (AS_LDS void*)&Bs[r0][c0],    16, 0, 0);
    __builtin_amdgcn_global_load_lds((const AS_GLOBAL void*)(Brow1 + kb),
                                     (AS_LDS void*)&Bs[r0+64][c0], 16, 0, 0);
    __syncthreads();
    short8 af[2], bf[4];
    #pragma unroll
    for (int m=0;m<2;m++) af[m] = *(const short8*)&As[32*wr + 16*m + lrow][8*lhi];
    #pragma unroll
    for (int n=0;n<4;n++) bf[n] = *(const short8*)&Bs[64*wc + 16*n + lrow][8*lhi];
    #pragma unroll
    for (int m=0;m<2;m++)
      #pragma unroll
      for (int n=0;n<4;n++)
        acc[m][n] = __builtin_amdgcn_mfma_f32_16x16x32_bf16(af[m], bf[n], acc[m][n], 0,0,0);
    __syncthreads();
  }
#else
  for (int kb=0; kb<K; kb+=32){
    int4 a0 = *(const int4*)(Arow + kb);
    int4 b0 = *(const int4*)(Brow0 + kb);
    int4 b1 = *(const int4*)(Brow1 + kb);
    __syncthreads();
    *(int4*)&As[r0][c0]    = a0;
    *(int4*)&Bs[r0][c0]    = b0;
    *(int4*)&Bs[r0+64][c0] = b1;
    __syncthreads();
    short8 af[2], bf[4];
    #pragma unroll
    for (int m=0;m<2;m++) af[m] = *(const short8*)&As[32*wr + 16*m + lrow][8*lhi];
    #pragma unroll
    for (int n=0;n<4;n++) bf[n] = *(const short8*)&Bs[64*wc + 16*n + lrow][8*lhi];
    #pragma unroll
    for (int m=0;m<2;m++)
      #pragma unroll
      for (int n=0;n<4;n++)
        acc[m][n] = __builtin_amdgcn_mfma_f32_16x16x32_bf16(af[m], bf[n], acc[m][n], 0,0,0);
  }
#endif
  #pragma unroll
  for (int m=0;m<2;m++)
    #pragma unroll
    for (int n=0;n<4;n++)
      #pragma unroll
      for (int q=0;q<4;q++){
        int row = mb + 32*wr + 16*m + 4*lhi + q;
        int col = nb + 64*wc + 16*n + lrow;
        Cout[(size_t)row*N + col] = acc[m][n][q] + bias[col];
      }
}

// ---------------- post-QKV: rope, overwrites, v-scale; write Q,K,[VT transposed] ----------------
__global__ __launch_bounds__(256) void k_post(const unsigned short* __restrict__ qkv,
                                              const float* __restrict__ cos_t,
                                              const float* __restrict__ sin_t,
                                              const float* __restrict__ cum,
                                              unsigned short* __restrict__ Q,
                                              unsigned short* __restrict__ K,
                                              unsigned short* __restrict__ VT){
  __shared__ unsigned short vt[64][66];
  int b = blockIdx.z, h = blockIdx.y, tb = blockIdx.x*64;
  int d0 = threadIdx.x & 31, tsub = threadIdx.x >> 5; // 32 x 8
  const float scale = 0.125f;
  #pragma unroll
  for (int i=0;i<8;i++){
    int t = tb + tsub + i*8;
    size_t rowoff = ((size_t)b*Tt + t)*3*Cc + (size_t)h*HDd;
    float c = cos_t[((size_t)b*Tt + t)*32 + d0];
    float s = sin_t[((size_t)b*Tt + t)*32 + d0];
    float q0 = bf2f(qkv[rowoff + d0]);
    float q1 = bf2f(qkv[rowoff + d0 + 32]);
    float k0 = bf2f(qkv[rowoff + Cc + d0]);
    float k1 = bf2f(qkv[rowoff + Cc + d0 + 32]);
    float v0 = bf2f(qkv[rowoff + 2*Cc + d0]);
    float v1 = bf2f(qkv[rowoff + 2*Cc + d0 + 32]);
    float qa = q0*c - q1*s, qb = q1*c + q0*s;
    float ka = k0*c - k1*s, kb = k1*c + k0*s;
    float cs = cum[b*Tt + t];
    if (d0 == 31){ qb = 1.0f; kb = cs; }   // last dim (d=63) overwrites, post-rope
    qa *= scale; qb *= scale;              // fold softmax scale into Q
    float ev = expf(cs);
    v0 *= ev; v1 *= ev;
    size_t qrow = (((size_t)b*Hh + h)*Tt + t)*HDd;
    Q[qrow + d0]      = f2bf(qa);
    Q[qrow + d0 + 32] = f2bf(qb);
    K[qrow + d0]      = f2bf(ka);
    K[qrow + d0 + 32] = f2bf(kb);
    vt[tsub + i*8][d0]      = f2bf(v0);
    vt[tsub + i*8][d0 + 32] = f2bf(v1);
  }
  __syncthreads();
  #pragma unroll
  for (int i=0;i<16;i++){
    int d  = (threadIdx.x >> 6) + i*4;
    int ttl = threadIdx.x & 63;
    VT[(((size_t)b*Hh + h)*HDd + d)*Tt + tb + ttl] = vt[ttl][d];
  }
}

// ---------------- flash attention v7: in-block split-k, 8 waves, 4 waves/SIMD ----------------
// Waves 0-3 (p=0) take even k-tiles, 4-7 (p=1) odd; fixed-m softmax makes O,l
// partials additive -> combine once at the end via LDS. Each iteration stages
// TWO tiles (K+V, 32KB) via global_load_lds; one barrier per 2 tiles.
__global__ __launch_bounds__(512, 4) void k_attn7(const unsigned short* __restrict__ Q,
                                                  const unsigned short* __restrict__ K,
                                                  const unsigned short* __restrict__ VT,
                                                  unsigned short* __restrict__ Y){
  __shared__ __align__(16) char smem[65536];
  typedef unsigned short (*tile_t)[2][4096];
  tile_t Ks = (tile_t)smem;                 // Ks[buf][slot][4096]
  tile_t Vs = (tile_t)(smem + 32768);
  float (*cmb)[64][35] = (float (*)[64][35])smem;   // overlay, used after final barrier

  int bh = blockIdx.y; int b = bh >> 4, h = bh & 15;
  int tid = threadIdx.x;
  int wave = tid>>6, lane = tid&63;
  int wpair = wave & 3, p = wave >> 2;
  int lrow = lane&15, lhi = lane>>4;
  const unsigned short* Qh = Q + (((size_t)b*Hh + h)*Tt)*HDd;
  const unsigned short* Kh = K + (((size_t)b*Hh + h)*Tt)*HDd;
  const unsigned short* Vh = VT + (((size_t)b*Hh + h)*HDd)*Tt;
  int s_ = blockIdx.x;                      // 0..15
  int qL0 = 64*s_ + 16*wpair;               // low strip rows
  int qH0 = 1984 - 64*s_ + 16*wpair;        // mirrored high strip rows
  short8 qfL0 = *(const short8*)&Qh[(size_t)(qL0+lrow)*HDd + 8*lhi];
  short8 qfL1 = *(const short8*)&Qh[(size_t)(qL0+lrow)*HDd + 32 + 8*lhi];
  short8 qfH0 = *(const short8*)&Qh[(size_t)(qH0+lrow)*HDd + 8*lhi];
  short8 qfH1 = *(const short8*)&Qh[(size_t)(qH0+lrow)*HDd + 32 + 8*lhi];
  f32x4 oL[4] = {}, oH[4] = {};             // [d-tile jp], rows q=4*lhi+r
  float lsL = 0.0f, lsH = 0.0f;             // per-lane l partial for q=lrow
  int rowL = qL0 + lrow, rowH = qH0 + lrow;
  int ntL = s_ + 1;                         // L tiles (uniform over waves)
  int NTH = 32 - s_;                        // H tiles (uniform over waves)
  int NI  = (NTH + 1) >> 1;                 // iterations (2 tiles each)

  // staging geometry: 512 threads x 16B = one 8KB subtile per round
  int kr = tid >> 3, kc = tid & 7;          // row 0..63, 16B col-group 0..7
  int o_ = tid * 16;                        // linear LDS byte offset in subtile
  int ksrc = kr*HDd + ((kc ^ (kr&7)) << 3); // inverse-swizzled global source (elems)
  int vsrc = kr*Tt  + ((kc ^ (kr&7)) << 3);

#ifdef USE_GLL
#define STAGE2(bufi, base_) do { \
    __builtin_amdgcn_global_load_lds((const AS_GLOBAL void*)(Kh + (size_t)(base_)*64*HDd + ksrc), \
        (AS_LDS void*)((AS_LDS char*)&Ks[bufi][0][0] + o_), 16, 0, 0); \
    __builtin_amdgcn_global_load_lds((const AS_GLOBAL void*)(Vh + (size_t)(base_)*64 + vsrc), \
        (AS_LDS void*)((AS_LDS char*)&Vs[bufi][0][0] + o_), 16, 0, 0); \
    if ((base_)+1 < NTH){ \
      __builtin_amdgcn_global_load_lds((const AS_GLOBAL void*)(Kh + (size_t)((base_)+1)*64*HDd + ksrc), \
          (AS_LDS void*)((AS_LDS char*)&Ks[bufi][1][0] + o_), 16, 0, 0); \
      __builtin_amdgcn_global_load_lds((const AS_GLOBAL void*)(Vh + (size_t)((base_)+1)*64 + vsrc), \
          (AS_LDS void*)((AS_LDS char*)&Vs[bufi][1][0] + o_), 16, 0, 0); \
    } \
  } while(0)
#else
#define STAGE2(bufi, base_) do { \
    int4 a_ = *(const int4*)(Kh + (size_t)(base_)*64*HDd + ksrc); \
    int4 c_ = *(const int4*)(Vh + (size_t)(base_)*64 + vsrc); \
    *(int4*)((char*)&Ks[bufi][0][0] + o_) = a_; \
    *(int4*)((char*)&Vs[bufi][0][0] + o_) = c_; \
    if ((base_)+1 < NTH){ \
      int4 b_ = *(const int4*)(Kh + (size_t)((base_)+1)*64*HDd + ksrc); \
      int4 d_ = *(const int4*)(Vh + (size_t)((base_)+1)*64 + vsrc); \
      *(int4*)((char*)&Ks[bufi][1][0] + o_) = b_; \
      *(int4*)((char*)&Vs[bufi][1][0] + o_) = d_; \
    } \
  } while(0)
#endif

  STAGE2(0, 0);
  int buf = 0;
  for (int i = 0; i < NI; i++){
    __syncthreads();                         // buf staged; prior reads of buf^1 done
    if (i+1 < NI) STAGE2(buf^1, 2*(i+1));
    int kt = 2*i + p;
    if (kt < NTH){
      int k0 = kt*64;
      bool doL = (kt < ntL);
      const unsigned short* Kbase = &Ks[buf][p][0];
      const unsigned short* Vbase = &Vs[buf][p][0];
      f32x4 sL[4] = {}, sH[4] = {};
      __builtin_amdgcn_s_setprio(1);
      #pragma unroll
      for (int j=0;j<4;j++){
        int krow = 16*j + lrow;
        #pragma unroll
        for (int ks=0;ks<2;ks++){
          int dgrp = (4*ks + lhi) ^ (krow&7);
          short8 kf = *(const short8*)&Kbase[krow*64 + dgrp*8];
          sH[j] = __builtin_amdgcn_mfma_f32_16x16x32_bf16(kf, ks ? qfH1 : qfH0, sH[j], 0,0,0);
          if (doL) sL[j] = __builtin_amdgcn_mfma_f32_16x16x32_bf16(kf, ks ? qfL1 : qfL0, sL[j], 0,0,0);
        }
      }
      __builtin_amdgcn_s_setprio(0);
      short4v paH[4], paL[4];
      {
        bool diagH = (k0 + 63 >= qH0);
        #pragma unroll
        for (int j=0;j<4;j++){
          int kbase = k0 + 16*j + 4*lhi;
          float p0 = __expf(sH[j][0]);
          float p1 = __expf(sH[j][1]);
          float p2 = __expf(sH[j][2]);
          float p3 = __expf(sH[j][3]);
          if (diagH){
            if (kbase + 0 > rowH) p0 = 0.0f;
            if (kbase + 1 > rowH) p1 = 0.0f;
            if (kbase + 2 > rowH) p2 = 0.0f;
            if (kbase + 3 > rowH) p3 = 0.0f;
          }
          lsH += (p0 + p1) + (p2 + p3);
          union { unsigned int u[2]; short4v v; } pk;
          pk.u[0] = cvtpk_bf16(p0, p1);
          pk.u[1] = cvtpk_bf16(p2, p3);
          paH[j] = pk.v;
        }
      }
      if (doL){
        bool diagL = (k0 + 63 >= qL0);
        #pragma unroll
        for (int j=0;j<4;j++){
          int kbase = k0 + 16*j + 4*lhi;
          float p0 = __expf(sL[j][0]);
          float p1 = __expf(sL[j][1]);
          float p2 = __expf(sL[j][2]);
          float p3 = __expf(sL[j][3]);
          if (diagL){
            if (kbase + 0 > rowL) p0 = 0.0f;
            if (kbase + 1 > rowL) p1 = 0.0f;
            if (kbase + 2 > rowL) p2 = 0.0f;
            if (kbase + 3 > rowL) p3 = 0.0f;
          }
          lsL += (p0 + p1) + (p2 + p3);
          union { unsigned int u[2]; short4v v; } pk;
          pk.u[0] = cvtpk_bf16(p0, p1);
          pk.u[1] = cvtpk_bf16(p2, p3);
          paL[j] = pk.v;
        }
      }
      __builtin_amdgcn_s_setprio(1);
      #pragma unroll
      for (int jp=0;jp<4;jp++){
        int vrow = 16*jp + lrow;
        #pragma unroll
        for (int j=0;j<4;j++){
          int byte_in_row = ((((2*j + (lhi>>1)) ^ (vrow&7)) << 4) | ((lhi&1) << 3));
          short4v vf = *(const short4v*)((const char*)&Vbase[vrow*64] + byte_in_row);
          oH[jp] = mfma16(paH[j], vf, oH[jp]);
          if (doL) oL[jp] = mfma16(paL[j], vf, oL[jp]);
        }
      }
      __builtin_amdgcn_s_setprio(0);
    }
    buf ^= 1;
  }

  // ---- combine the two k-parities via LDS, then reduce + write (p==0 waves) ----
  __syncthreads();                           // all tile compute done; smem reusable
  if (p == 1){
    float* c = &cmb[wpair][lane][0];
    #pragma unroll
    for (int jp=0;jp<4;jp++)
      #pragma unroll
      for (int r=0;r<4;r++){
        c[4*jp+r]      = oL[jp][r];
        c[16+4*jp+r]   = oH[jp][r];
      }
    c[32] = lsL; c[33] = lsH;
  }
  __syncthreads();
  if (p == 0){
    const float* c = &cmb[wpair][lane][0];
    #pragma unroll
    for (int jp=0;jp<4;jp++)
      #pragma unroll
      for (int r=0;r<4;r++){
        oL[jp][r] += c[4*jp+r];
        oH[jp][r] += c[16+4*jp+r];
      }
    lsL += c[32]; lsH += c[33];
    lsL += __shfl_xor(lsL, 16); lsL += __shfl_xor(lsL, 32);
    lsH += __shfl_xor(lsH, 16); lsH += __shfl_xor(lsH, 32);
    float invLl = 1.0f / lsL, invHl = 1.0f / lsH;
    float invLr[4], invHr[4];
    #pragma unroll
    for (int r=0;r<4;r++){
      invLr[r] = __shfl(invLl, 4*lhi + r);
      invHr[r] = __shfl(invHl, 4*lhi + r);
    }
    #pragma unroll
    for (int jp=0;jp<4;jp++)
      #pragma unroll
      for (int r=0;r<4;r++){
        int rqL = qL0 + 4*lhi + r;
        int rqH = qH0 + 4*lhi + r;
        int col = h*HDd + 16*jp + lrow;
        Y[((size_t)b*Tt + rqL)*Cc + col] = f2bf(oL[jp][r] * invLr[r]);
        Y[((size_t)b*Tt + rqH)*Cc + col] = f2bf(oH[jp][r] * invHr[r]);
      }
  }
#undef STAGE2
}

extern "C" void kernel_launch(void* const* d_in, const int* in_sizes, int n_in,
                              void* d_out, int out_size, void* d_ws, size_t ws_size,
                              hipStream_t stream){
  const float* x     = (const float*)d_in[0];
  const float* cum   = (const float*)d_in[1];
  const int*   tok   = (const int*)d_in[3];
  const float* Wqkv  = (const float*)d_in[4];
  const float* bqkv  = (const float*)d_in[5];
  const float* Wproj = (const float*)d_in[6];
  const float* bproj = (const float*)d_in[7];

  char* ws = (char*)d_ws;
  size_t off = 0;
  auto alloc = [&](size_t bytes)->void*{
    void* p = ws + off; off += (bytes + 255) & ~(size_t)255; return p;
  };
  unsigned short* wqkvT = (unsigned short*)alloc((size_t)3072*1024*2);
  unsigned short* wprojT= (unsigned short*)alloc((size_t)1024*1024*2);
  unsigned short* xb    = (unsigned short*)alloc((size_t)4096*1024*2); // reused as Y
  unsigned short* qkv   = (unsigned short*)alloc((size_t)4096*3072*2);
  unsigned short* Qb    = (unsigned short*)alloc((size_t)Bb*Hh*Tt*HDd*2);
  unsigned short* Kb    = (unsigned short*)alloc((size_t)Bb*Hh*Tt*HDd*2);
  unsigned short* VTb   = (unsigned short*)alloc((size_t)Bb*Hh*Tt*HDd*2);
  float* rot            = (float*)alloc((size_t)Bb*Tt*4);
  float* cos_t          = (float*)alloc((size_t)Bb*Tt*32*4);
  float* sin_t          = (float*)alloc((size_t)Bb*Tt*32*4);
  unsigned short* Y     = xb; // alias: xb dead after QKV GEMM

  k_f2b<<<dim3((4096*1024/4 + 255)/256), dim3(256), 0, stream>>>(x, xb, 4096*1024);
  k_transpose_f2b<<<dim3(3072/32, 1024/32), dim3(32,8), 0, stream>>>(Wqkv, wqkvT, 1024, 3072);
  k_transpose_f2b<<<dim3(1024/32, 1024/32), dim3(32,8), 0, stream>>>(Wproj, wprojT, 1024, 1024);
  k_scan<<<dim3(Bb), dim3(1024), 0, stream>>>(tok, rot);
  k_tables<<<dim3(Bb*Tt*32/256), dim3(256), 0, stream>>>(rot, cos_t, sin_t);
  k_gemm128<0><<<dim3(3072/128, 4096/128), dim3(256), 0, stream>>>(xb, wqkvT, bqkv, qkv, 4096, 3072, 1024);
  k_post<<<dim3(Tt/64, Hh, Bb), dim3(256), 0, stream>>>(qkv, cos_t, sin_t, cum, Qb, Kb, VTb);
  k_attn7<<<dim3(16, Bb*Hh), dim3(512), 0, stream>>>(Qb, Kb, VTb, Y);
  k_gemm64<<<dim3(1024/128, 4096/64), dim3(256), 0, stream>>>(Y, wprojT, bproj, (float*)d_out, 4096, 1024, 1024);
}